// Round 6
// baseline (992.686 us; speedup 1.0000x reference)
//
#include <hip/hip_runtime.h>
#include <math.h>

#define BATCH 16
#define GRID  80
#define NANCH 3
#define KTOP  300
#define NBOX  (NANCH*GRID*GRID)   // 19200
#define SORT_CAP 8192

__device__ __forceinline__ float sigmoidf_(float x){ return 1.0f/(1.0f+expf(-x)); }

// ---------------- tiled 3x3 stride-2 conv + SiLU, v2 ----------------
// block = 256 threads -> 32x32 output tile, 2x2 pixels/thread, NOC oc/thread.
// Weights staged once into LDS (stride 12 -> b128 reads, broadcast).
// Input halo 65x65 in LDS with odd row stride 67 (<=2-way bank aliasing).
template<int CIN, int COUT, int NOC, int IC_CHUNK, int HIN, int HOUT>
__global__ __launch_bounds__(256, 2) void conv3x3s2_v2(
    const float* __restrict__ in, const float* __restrict__ w,
    const float* __restrict__ bias, float* __restrict__ out)
{
  constexpr int TILES = (HOUT + 31) / 32;
  constexpr bool MASK  = (TILES * 32 != HOUT);
  constexpr int ILDS_C = 65 * 67;            // 4355 floats per channel
  __shared__ float ilds[IC_CHUNK * ILDS_C];
  __shared__ float wlds[NOC * CIN * 12];

  const int t  = threadIdx.x;
  const int tx = t & 15, ty = t >> 4;
  int blk = blockIdx.x;
  const int bx  = blk % TILES; blk /= TILES;
  const int by  = blk % TILES; blk /= TILES;
  const int b   = blk % BATCH; blk /= BATCH;
  const int ocg = blk;

  const int ix0 = bx * 64, iy0 = by * 64;

  // ---- stage weights once: w[(ocg*NOC+oc)][ic][9] -> wlds[(oc*CIN+ic)*12+k]
  for (int i = t; i < NOC * CIN * 9; i += 256){
    int oc = i / (CIN * 9);
    int r  = i - oc * (CIN * 9);
    int ic = r / 9, k = r - ic * 9;
    wlds[(oc * CIN + ic) * 12 + k] = w[((size_t)(ocg * NOC + oc) * CIN + ic) * 9 + k];
  }

  float acc[2][2][NOC];
  #pragma unroll
  for (int py = 0; py < 2; ++py)
    #pragma unroll
    for (int px = 0; px < 2; ++px)
      #pragma unroll
      for (int oc = 0; oc < NOC; ++oc)
        acc[py][px][oc] = bias[ocg * NOC + oc];

  const int lx0 = 2 * tx, ly0 = 2 * ty;

  for (int c0 = 0; c0 < CIN; c0 += IC_CHUNK){
    __syncthreads();            // protects wlds on first pass, ilds reuse later
    // ---- stage input halo: 65x65 per channel, row stride 67
    for (int i = t; i < IC_CHUNK * 65 * 65; i += 256){
      int c  = i / (65 * 65);
      int r  = i - c * (65 * 65);
      int yy = r / 65, xx = r - yy * 65;
      int iy = iy0 + yy, ix = ix0 + xx;
      float v = 0.0f;
      if (iy < HIN && ix < HIN)
        v = in[((size_t)(b * CIN + c0 + c) * HIN + iy) * HIN + ix];
      ilds[c * ILDS_C + yy * 67 + xx] = v;
    }
    __syncthreads();

    #pragma unroll
    for (int ic = 0; ic < IC_CHUNK; ++ic){
      const float* ip = ilds + ic * ILDS_C;
      // 6x6 input micro-tile: rows {2ty+0..2, 2ty+32..34}, cols likewise
      float v[6][6];
      #pragma unroll
      for (int a = 0; a < 6; ++a){
        int ly = ly0 + (a >= 3 ? 32 : 0) + (a % 3);
        #pragma unroll
        for (int c = 0; c < 6; ++c){
          int lx = lx0 + (c >= 3 ? 32 : 0) + (c % 3);
          v[a][c] = ip[ly * 67 + lx];
        }
      }
      #pragma unroll
      for (int oc = 0; oc < NOC; ++oc){
        const float* wp = &wlds[(oc * CIN + (c0 + ic)) * 12];
        float wv[9];
        #pragma unroll
        for (int k = 0; k < 9; ++k) wv[k] = wp[k];
        #pragma unroll
        for (int py = 0; py < 2; ++py)
          #pragma unroll
          for (int px = 0; px < 2; ++px)
            #pragma unroll
            for (int ky = 0; ky < 3; ++ky)
              #pragma unroll
              for (int kx = 0; kx < 3; ++kx)
                acc[py][px][oc] += v[py*3+ky][px*3+kx] * wv[ky*3+kx];
      }
    }
  }

  // ---- epilogue: SiLU + store (coalesced along tx)
  #pragma unroll
  for (int oc = 0; oc < NOC; ++oc){
    #pragma unroll
    for (int py = 0; py < 2; ++py){
      int oy = by * 32 + ty + 16 * py;
      #pragma unroll
      for (int px = 0; px < 2; ++px){
        int ox = bx * 32 + tx + 16 * px;
        if (!MASK || (oy < HOUT && ox < HOUT)){
          float z = acc[py][px][oc];
          float s = 1.0f / (1.0f + expf(-z));
          out[((size_t)(b * COUT + ocg * NOC + oc) * HOUT + oy) * HOUT + ox] = z * s;
        }
      }
    }
  }
}

// ---------------- 1x1 head (6 needed channels) + sigmoid + decode ----------------
__global__ __launch_bounds__(256) void decode_kernel(
    const float* __restrict__ f3, const float* __restrict__ Wh,
    const float* __restrict__ bh, float* __restrict__ boxes,
    float* __restrict__ scores)
{
  int idx = blockIdx.x*256 + threadIdx.x;
  const int total = BATCH*NANCH*GRID*GRID;
  if (idx >= total) return;
  int gx = idx % GRID;
  int gy = (idx/GRID)%GRID;
  int a  = (idx/(GRID*GRID))%NANCH;
  int b  = idx/(GRID*GRID*NANCH);
  const float aw[3] = {4.0f, 8.0f, 13.0f};
  const float ah[3] = {5.0f, 10.0f, 16.0f};
  const int   chs[6] = {0,1,2,3,4,15};
  const float* f = f3 + (size_t)b*64*GRID*GRID + (size_t)gy*GRID + gx;
  float acc[6];
  #pragma unroll
  for (int j=0;j<6;j++) acc[j] = bh[a*16 + chs[j]];
  for (int ic=0; ic<64; ++ic){
    float v = f[(size_t)ic*GRID*GRID];
    #pragma unroll
    for (int j=0;j<6;j++) acc[j] += v * Wh[(size_t)(a*16+chs[j])*64 + ic];
  }
  float p0 = sigmoidf_(acc[0]);
  float p1 = sigmoidf_(acc[1]);
  float p2 = sigmoidf_(acc[2]);
  float p3 = sigmoidf_(acc[3]);
  float p4 = sigmoidf_(acc[4]);
  float p15= sigmoidf_(acc[5]);
  float cx = (p0*2.0f - 0.5f + (float)gx)*8.0f;
  float cy = (p1*2.0f - 0.5f + (float)gy)*8.0f;
  float ww = p2*2.0f; ww = ww*ww*aw[a];
  float hh = p3*2.0f; hh = hh*hh*ah[a];
  float sc = p4*p15;
  sc = (sc > 0.5f) ? sc : 0.0f;
  int bi = a*GRID*GRID + gy*GRID + gx;
  float* bo = boxes + ((size_t)b*NBOX + bi)*4;
  bo[0] = cx - ww*0.5f;
  bo[1] = cy - hh*0.5f;
  bo[2] = cx + ww*0.5f;
  bo[3] = cy + hh*0.5f;
  scores[(size_t)b*NBOX + bi] = sc;
}

// ---------------- kernel A: compact + bitonic-sort top-K + gather ----------------
__global__ __launch_bounds__(1024) void topk_kernel(
    const float* __restrict__ boxes, const float* __restrict__ scores,
    float* __restrict__ nmsbuf, int* __restrict__ mcnt)
{
  __shared__ unsigned long long keys[SORT_CAP];  // 64 KB
  __shared__ int   cntM;
  __shared__ int   sel[KTOP];
  __shared__ float selsc[KTOP];
  __shared__ int   wsum[16];
  __shared__ float rs[16];
  __shared__ int   ri[16];
  __shared__ unsigned clm[(NBOX+31)/32];         // fallback claimed bitmask

  const int b = blockIdx.x;
  const int t = threadIdx.x;
  const int lane = t & 63, wv = t >> 6;
  const float* scp = scores + (size_t)b*NBOX;

  if (t == 0) cntM = 0;
  __syncthreads();

  for (int i=t; i<NBOX; i+=1024){
    float v = scp[i];
    if (v > 0.0f){
      int p = atomicAdd(&cntM, 1);
      if (p < SORT_CAP)
        keys[p] = ((unsigned long long)__float_as_uint(v) << 32)
                | (unsigned)(0xFFFFFFFFu - (unsigned)i);
    }
  }
  __syncthreads();
  const int M = cntM;
  if (t == 0) mcnt[b] = M;

  if (M <= SORT_CAP){
    int P = 64; while (P < M) P <<= 1;
    for (int i=t; i<P; i+=1024) if (i >= M) keys[i] = 0ULL;
    __syncthreads();
    for (int k=2; k<=P; k<<=1){
      for (int j=k>>1; j>0; j>>=1){
        for (int i=t; i<P; i+=1024){
          int ixj = i ^ j;
          if (ixj > i){
            unsigned long long a = keys[i], c = keys[ixj];
            bool up = ((i & k) == 0);
            if (up ? (a < c) : (a > c)){ keys[i] = c; keys[ixj] = a; }
          }
        }
        __syncthreads();
      }
    }
    const int top = (M < KTOP) ? M : KTOP;
    if (t < top){
      unsigned long long kk = keys[t];
      selsc[t] = __uint_as_float((unsigned)(kk >> 32));
      sel[t]   = (int)(0xFFFFFFFFu - (unsigned)(kk & 0xFFFFFFFFu));
    }
    if (M < KTOP){
      const int need = KTOP - M;
      const int C = (NBOX + 1023)/1024;   // 19
      int lo = t*C, hi = lo+C; if (hi > NBOX) hi = NBOX; if (lo > NBOX) lo = NBOX;
      int zc = 0;
      for (int i=lo;i<hi;i++) if (scp[i] <= 0.0f) zc++;
      int v = zc;
      #pragma unroll
      for (int off=1; off<64; off<<=1){
        int n = __shfl_up(v, off);
        if (lane >= off) v += n;
      }
      if (lane == 63) wsum[wv] = v;
      __syncthreads();
      if (t == 0){
        int a = 0;
        for (int w=0; w<16; w++){ int tmp = wsum[w]; wsum[w] = a; a += tmp; }
      }
      __syncthreads();
      int r = wsum[wv] + v - zc;
      for (int i=lo;i<hi;i++){
        if (scp[i] <= 0.0f){
          if (r < need){ sel[M+r] = i; selsc[M+r] = 0.0f; }
          r++;
        }
      }
    }
    __syncthreads();
  } else {
    for (int i=t; i<(NBOX+31)/32; i+=1024) clm[i] = 0u;
    __syncthreads();
    for (int k=0;k<KTOP;k++){
      float best = -2.0f; int bi = NBOX;
      for (int i=t;i<NBOX;i+=1024){
        if (!((clm[i>>5] >> (i&31)) & 1u)){
          float v = scp[i];
          if (v > best){ best=v; bi=i; }
        }
      }
      #pragma unroll
      for (int off=32; off>0; off>>=1){
        float ov = __shfl_down(best, off);
        int   oi = __shfl_down(bi,   off);
        if (ov > best || (ov == best && oi < bi)){ best=ov; bi=oi; }
      }
      if (lane == 0){ rs[wv]=best; ri[wv]=bi; }
      __syncthreads();
      if (t == 0){
        for (int w=1; w<16; w++)
          if (rs[w] > best || (rs[w] == best && ri[w] < bi)){ best=rs[w]; bi=ri[w]; }
        sel[k]=bi; selsc[k]=best; clm[bi>>5] |= (1u << (bi&31));
      }
      __syncthreads();
    }
  }

  if (t < KTOP){
    const float* bp = boxes + ((size_t)b*NBOX + sel[t])*4;
    float x1=bp[0], y1=bp[1], x2=bp[2], y2=bp[3];
    float* o = nmsbuf + ((size_t)b*KTOP + t)*6;
    o[0]=x1; o[1]=y1; o[2]=x2; o[3]=y2;
    o[4]=selsc[t];
    o[5]=fmaxf(x2-x1,0.0f)*fmaxf(y2-y1,0.0f);
  }
}

// ---------------- kernel B: single-wave register NMS + final write ----------------
__global__ __launch_bounds__(64, 1) void nms_kernel(
    const float* __restrict__ nmsbuf, const int* __restrict__ mcnt,
    float* __restrict__ out)
{
  const int b = blockIdx.x;
  const int lane = threadIdx.x;
  int Mtop = mcnt[b]; if (Mtop > KTOP) Mtop = KTOP;
  float X1[5],Y1[5],X2[5],Y2[5],AR[5],SC[5];
  unsigned keepm = 0;
  #pragma unroll
  for (int s5=0; s5<5; ++s5){
    int j = lane + 64*s5;
    if (j < KTOP){
      const float* p = nmsbuf + ((size_t)b*KTOP + j)*6;
      X1[s5]=p[0]; Y1[s5]=p[1]; X2[s5]=p[2]; Y2[s5]=p[3];
      SC[s5]=p[4]; AR[s5]=p[5];
      keepm |= (1u << s5);
    } else { X1[s5]=0;Y1[s5]=0;X2[s5]=0;Y2[s5]=0;AR[s5]=0;SC[s5]=0; }
  }
  for (int i=0;i<Mtop;i++){
    const int iw = i & 63, is = i >> 6;           // wave-uniform
    unsigned km = __shfl(keepm, iw);
    if ((km >> is) & 1u){
      float sx1 = (is==0)?X1[0]:(is==1)?X1[1]:(is==2)?X1[2]:(is==3)?X1[3]:X1[4];
      float sy1 = (is==0)?Y1[0]:(is==1)?Y1[1]:(is==2)?Y1[2]:(is==3)?Y1[3]:Y1[4];
      float sx2 = (is==0)?X2[0]:(is==1)?X2[1]:(is==2)?X2[2]:(is==3)?X2[3]:X2[4];
      float sy2 = (is==0)?Y2[0]:(is==1)?Y2[1]:(is==2)?Y2[2]:(is==3)?Y2[3]:Y2[4];
      float sa  = (is==0)?AR[0]:(is==1)?AR[1]:(is==2)?AR[2]:(is==3)?AR[3]:AR[4];
      float bx1=__shfl(sx1,iw), by1=__shfl(sy1,iw);
      float bx2=__shfl(sx2,iw), by2=__shfl(sy2,iw);
      float ba =__shfl(sa ,iw);
      #pragma unroll
      for (int s5=0; s5<5; ++s5){
        int j = lane + 64*s5;
        if (((keepm >> s5) & 1u) && j > i){
          float ix1=fmaxf(bx1,X1[s5]);
          float iy1=fmaxf(by1,Y1[s5]);
          float ix2=fminf(bx2,X2[s5]);
          float iy2=fminf(by2,Y2[s5]);
          float inter=fmaxf(ix2-ix1,0.0f)*fmaxf(iy2-iy1,0.0f);
          float iou = inter/(ba+AR[s5]-inter+1e-7f);
          if (iou > 0.5f) keepm &= ~(1u << s5);
        }
      }
    }
  }
  #pragma unroll
  for (int s5=0; s5<5; ++s5){
    int j = lane + 64*s5;
    if (j < KTOP){
      float scv = SC[s5];
      float kf  = (((keepm >> s5) & 1u) && scv > 0.0f) ? 1.0f : 0.0f;
      float* o = out + ((size_t)b*KTOP + j)*6;
      o[0]=X1[s5]; o[1]=Y1[s5]; o[2]=X2[s5]; o[3]=Y2[s5];
      o[4]=scv; o[5]=kf;
    }
  }
}

extern "C" void kernel_launch(void* const* d_in, const int* in_sizes, int n_in,
                              void* d_out, int out_size, void* d_ws, size_t ws_size,
                              hipStream_t stream) {
  const float* x  = (const float*)d_in[0];
  const float* W1 = (const float*)d_in[1];
  const float* b1 = (const float*)d_in[2];
  const float* W2 = (const float*)d_in[3];
  const float* b2 = (const float*)d_in[4];
  const float* W3 = (const float*)d_in[5];
  const float* b3 = (const float*)d_in[6];
  const float* Wh = (const float*)d_in[7];
  const float* bh = (const float*)d_in[8];
  float* out = (float*)d_out;
  float* ws  = (float*)d_ws;

  float* f1     = ws;               // 16x16x320x320 = 26,214,400
  float* f2     = ws + 26214400;    // 16x32x160x160 = 13,107,200
  float* f3     = ws;               // reuse f1: 16x64x80x80
  float* boxes  = ws + 26214400;    // reuse f2: 16x19200x4
  float* scores = boxes + 1228800;  // 16x19200
  float* nmsbuf = scores + 307200;  // 16x300x6 = 28,800
  int*   mcnt   = (int*)(nmsbuf + 28800);

  // conv1: 3->16, 640->320.  tiles 10x10, NOC=16 (1 ocg), IC_CHUNK=3
  conv3x3s2_v2<3,16,16,3,640,320><<<10*10*BATCH*1, 256, 0, stream>>>(x,  W1, b1, f1);
  // conv2: 16->32, 320->160. tiles 5x5, NOC=16 (2 ocg), IC_CHUNK=2
  conv3x3s2_v2<16,32,16,2,320,160><<<5*5*BATCH*2, 256, 0, stream>>>(f1, W2, b2, f2);
  // conv3: 32->64, 160->80.  tiles 3x3 (masked), NOC=8 (8 ocg), IC_CHUNK=2
  conv3x3s2_v2<32,64,8,2,160,80><<<3*3*BATCH*8, 256, 0, stream>>>(f2, W3, b3, f3);

  decode_kernel<<<(BATCH*NANCH*GRID*GRID+255)/256, 256, 0, stream>>>(f3, Wh, bh, boxes, scores);
  topk_kernel<<<BATCH, 1024, 0, stream>>>(boxes, scores, nmsbuf, mcnt);
  nms_kernel<<<BATCH, 64, 0, stream>>>(nmsbuf, mcnt, out);
}

// Round 7
// 586.274 us; speedup vs baseline: 1.6932x; 1.6932x over previous
//
#include <hip/hip_runtime.h>
#include <math.h>

#define BATCH 16
#define GRID  80
#define NANCH 3
#define KTOP  300
#define NBOX  (NANCH*GRID*GRID)   // 19200
#define SORT_CAP 8192

__device__ __forceinline__ float sigmoidf_(float x){ return 1.0f/(1.0f+expf(-x)); }

// ---------------- 3x3 stride-2 conv + SiLU, v3 ----------------
// One block = TX x TY output tile x ALL COUT channels (no halo duplication).
// 256 threads = (NTX x NTY spatial) x OCG oc-groups; per thread 4x2 px, C oc.
// Inputs via ds_read_b128 rows (aligned, padded stride); weights staged to LDS
// (stride 12 -> 3 x b128/oc), read per-oc so only 12 weight regs live.
template<int CIN,int COUT,int C,int ICCH,int HIN,int HOUT,int TX,int TY>
__global__ __launch_bounds__(256, 1) void conv3x3s2_v3(
    const float* __restrict__ in, const float* __restrict__ w,
    const float* __restrict__ bias, float* __restrict__ out)
{
  constexpr int NTX = TX/4, NTY = TY/2, NSP = NTX*NTY, OCG = COUT/C;
  static_assert(NSP*OCG == 256, "bad thread layout");
  constexpr int HR = 2*TY+1, HC = 2*TX+1;
  constexpr int PADC = ((HC+3)/4)*4;      // 16B-aligned row stride
  constexpr int ILDSC = HR*PADC;
  constexpr int TBX = HOUT/TX, TBY = HOUT/TY;
  static_assert(TBX*TX == HOUT && TBY*TY == HOUT, "no masking");
  __shared__ float ilds[ICCH*ILDSC];
  __shared__ float wlds[COUT*ICCH*12];

  const int t  = threadIdx.x;
  const int sx = t % NTX;
  const int sy = (t / NTX) % NTY;
  const int og = t / NSP;                 // high bits -> wave-uniform(ish)
  int blk = blockIdx.x;
  const int bx = blk % TBX; blk /= TBX;
  const int by = blk % TBY; blk /= TBY;
  const int b  = blk;

  const int ix0 = bx*2*TX, iy0 = by*2*TY;

  float acc[C][2][4];
  #pragma unroll
  for (int j=0;j<C;++j){
    float bv = bias[og*C+j];
    #pragma unroll
    for (int py=0;py<2;++py)
      #pragma unroll
      for (int px=0;px<4;++px) acc[j][py][px]=bv;
  }

  for (int c0=0; c0<CIN; c0+=ICCH){
    __syncthreads();
    // ---- stage input halo (rows HR x cols HC, stride PADC)
    #pragma unroll 1
    for (int c=0;c<ICCH;++c){
      const float* gp = in + (size_t)(b*CIN + c0 + c)*HIN*HIN;
      for (int i=t; i<HR*HC; i+=256){
        int r = i/HC, cc = i - r*HC;
        int iy = iy0+r, ix = ix0+cc;
        float v = 0.0f;
        if (iy<HIN && ix<HIN) v = gp[(size_t)iy*HIN+ix];
        ilds[c*ILDSC + r*PADC + cc] = v;
      }
    }
    // ---- stage weights for this chunk: wlds[oc][icl][12]
    for (int i=t; i<COUT*ICCH*9; i+=256){
      int oc = i/(ICCH*9); int r = i - oc*(ICCH*9);
      int icl = r/9, k = r - icl*9;
      wlds[(oc*ICCH+icl)*12 + k] = w[((size_t)oc*CIN + c0+icl)*9 + k];
    }
    __syncthreads();

    for (int icl=0; icl<ICCH; ++icl){
      const float* ip = ilds + icl*ILDSC + (4*sy)*PADC + 8*sx;
      float rowf[5][12];
      #pragma unroll
      for (int r=0;r<5;++r)
        #pragma unroll
        for (int m=0;m<3;++m){
          float4 v4 = *(const float4*)(ip + r*PADC + 4*m);
          rowf[r][4*m+0]=v4.x; rowf[r][4*m+1]=v4.y;
          rowf[r][4*m+2]=v4.z; rowf[r][4*m+3]=v4.w;
        }
      #pragma unroll
      for (int j=0;j<C;++j){
        const float4* wp = (const float4*)(wlds + ((og*C+j)*ICCH + icl)*12);
        float4 w0=wp[0], w1=wp[1], w2=wp[2];
        const float wk[9] = {w0.x,w0.y,w0.z,w0.w,w1.x,w1.y,w1.z,w1.w,w2.x};
        #pragma unroll
        for (int py=0;py<2;++py)
          #pragma unroll
          for (int ky=0;ky<3;++ky)
            #pragma unroll
            for (int px=0;px<4;++px)
              #pragma unroll
              for (int kx=0;kx<3;++kx)
                acc[j][py][px] += rowf[2*py+ky][2*px+kx] * wk[3*ky+kx];
      }
    }
  }

  // ---- epilogue: SiLU + float4 stores
  const int oxb = bx*TX + sx*4;
  #pragma unroll
  for (int j=0;j<C;++j){
    int oc = og*C+j;
    #pragma unroll
    for (int py=0;py<2;++py){
      int oy = by*TY + sy*2 + py;
      float4 o4;
      float z0=acc[j][py][0], z1=acc[j][py][1], z2=acc[j][py][2], z3=acc[j][py][3];
      o4.x = z0/(1.0f+expf(-z0));
      o4.y = z1/(1.0f+expf(-z1));
      o4.z = z2/(1.0f+expf(-z2));
      o4.w = z3/(1.0f+expf(-z3));
      *(float4*)(out + ((size_t)(b*COUT+oc)*HOUT + oy)*HOUT + oxb) = o4;
    }
  }
}

// ---------------- 1x1 head (6 needed channels) + sigmoid + decode ----------------
__global__ __launch_bounds__(256) void decode_kernel(
    const float* __restrict__ f3, const float* __restrict__ Wh,
    const float* __restrict__ bh, float* __restrict__ boxes,
    float* __restrict__ scores)
{
  int idx = blockIdx.x*256 + threadIdx.x;
  const int total = BATCH*NANCH*GRID*GRID;
  if (idx >= total) return;
  int gx = idx % GRID;
  int gy = (idx/GRID)%GRID;
  int a  = (idx/(GRID*GRID))%NANCH;
  int b  = idx/(GRID*GRID*NANCH);
  const float aw[3] = {4.0f, 8.0f, 13.0f};
  const float ah[3] = {5.0f, 10.0f, 16.0f};
  const int   chs[6] = {0,1,2,3,4,15};
  const float* f = f3 + (size_t)b*64*GRID*GRID + (size_t)gy*GRID + gx;
  float acc[6];
  #pragma unroll
  for (int j=0;j<6;j++) acc[j] = bh[a*16 + chs[j]];
  for (int ic=0; ic<64; ++ic){
    float v = f[(size_t)ic*GRID*GRID];
    #pragma unroll
    for (int j=0;j<6;j++) acc[j] += v * Wh[(size_t)(a*16+chs[j])*64 + ic];
  }
  float p0 = sigmoidf_(acc[0]);
  float p1 = sigmoidf_(acc[1]);
  float p2 = sigmoidf_(acc[2]);
  float p3 = sigmoidf_(acc[3]);
  float p4 = sigmoidf_(acc[4]);
  float p15= sigmoidf_(acc[5]);
  float cx = (p0*2.0f - 0.5f + (float)gx)*8.0f;
  float cy = (p1*2.0f - 0.5f + (float)gy)*8.0f;
  float ww = p2*2.0f; ww = ww*ww*aw[a];
  float hh = p3*2.0f; hh = hh*hh*ah[a];
  float sc = p4*p15;
  sc = (sc > 0.5f) ? sc : 0.0f;
  int bi = a*GRID*GRID + gy*GRID + gx;
  float* bo = boxes + ((size_t)b*NBOX + bi)*4;
  bo[0] = cx - ww*0.5f;
  bo[1] = cy - hh*0.5f;
  bo[2] = cx + ww*0.5f;
  bo[3] = cy + hh*0.5f;
  scores[(size_t)b*NBOX + bi] = sc;
}

// ---------------- kernel A: compact + bitonic-sort top-K + gather ----------------
__global__ __launch_bounds__(1024) void topk_kernel(
    const float* __restrict__ boxes, const float* __restrict__ scores,
    float* __restrict__ nmsbuf, int* __restrict__ mcnt)
{
  __shared__ unsigned long long keys[SORT_CAP];  // 64 KB
  __shared__ int   cntM;
  __shared__ int   sel[KTOP];
  __shared__ float selsc[KTOP];
  __shared__ int   wsum[16];
  __shared__ float rs[16];
  __shared__ int   ri[16];
  __shared__ unsigned clm[(NBOX+31)/32];         // fallback claimed bitmask

  const int b = blockIdx.x;
  const int t = threadIdx.x;
  const int lane = t & 63, wv = t >> 6;
  const float* scp = scores + (size_t)b*NBOX;

  if (t == 0) cntM = 0;
  __syncthreads();

  for (int i=t; i<NBOX; i+=1024){
    float v = scp[i];
    if (v > 0.0f){
      int p = atomicAdd(&cntM, 1);
      if (p < SORT_CAP)
        keys[p] = ((unsigned long long)__float_as_uint(v) << 32)
                | (unsigned)(0xFFFFFFFFu - (unsigned)i);
    }
  }
  __syncthreads();
  const int M = cntM;
  if (t == 0) mcnt[b] = M;

  if (M <= SORT_CAP){
    int P = 64; while (P < M) P <<= 1;
    for (int i=t; i<P; i+=1024) if (i >= M) keys[i] = 0ULL;
    __syncthreads();
    for (int k=2; k<=P; k<<=1){
      for (int j=k>>1; j>0; j>>=1){
        for (int i=t; i<P; i+=1024){
          int ixj = i ^ j;
          if (ixj > i){
            unsigned long long a = keys[i], c = keys[ixj];
            bool up = ((i & k) == 0);
            if (up ? (a < c) : (a > c)){ keys[i] = c; keys[ixj] = a; }
          }
        }
        __syncthreads();
      }
    }
    const int top = (M < KTOP) ? M : KTOP;
    if (t < top){
      unsigned long long kk = keys[t];
      selsc[t] = __uint_as_float((unsigned)(kk >> 32));
      sel[t]   = (int)(0xFFFFFFFFu - (unsigned)(kk & 0xFFFFFFFFu));
    }
    if (M < KTOP){
      const int need = KTOP - M;
      const int C = (NBOX + 1023)/1024;   // 19
      int lo = t*C, hi = lo+C; if (hi > NBOX) hi = NBOX; if (lo > NBOX) lo = NBOX;
      int zc = 0;
      for (int i=lo;i<hi;i++) if (scp[i] <= 0.0f) zc++;
      int v = zc;
      #pragma unroll
      for (int off=1; off<64; off<<=1){
        int n = __shfl_up(v, off);
        if (lane >= off) v += n;
      }
      if (lane == 63) wsum[wv] = v;
      __syncthreads();
      if (t == 0){
        int a = 0;
        for (int w=0; w<16; w++){ int tmp = wsum[w]; wsum[w] = a; a += tmp; }
      }
      __syncthreads();
      int r = wsum[wv] + v - zc;
      for (int i=lo;i<hi;i++){
        if (scp[i] <= 0.0f){
          if (r < need){ sel[M+r] = i; selsc[M+r] = 0.0f; }
          r++;
        }
      }
    }
    __syncthreads();
  } else {
    for (int i=t; i<(NBOX+31)/32; i+=1024) clm[i] = 0u;
    __syncthreads();
    for (int k=0;k<KTOP;k++){
      float best = -2.0f; int bi = NBOX;
      for (int i=t;i<NBOX;i+=1024){
        if (!((clm[i>>5] >> (i&31)) & 1u)){
          float v = scp[i];
          if (v > best){ best=v; bi=i; }
        }
      }
      #pragma unroll
      for (int off=32; off>0; off>>=1){
        float ov = __shfl_down(best, off);
        int   oi = __shfl_down(bi,   off);
        if (ov > best || (ov == best && oi < bi)){ best=ov; bi=oi; }
      }
      if (lane == 0){ rs[wv]=best; ri[wv]=bi; }
      __syncthreads();
      if (t == 0){
        for (int w=1; w<16; w++)
          if (rs[w] > best || (rs[w] == best && ri[w] < bi)){ best=rs[w]; bi=ri[w]; }
        sel[k]=bi; selsc[k]=best; clm[bi>>5] |= (1u << (bi&31));
      }
      __syncthreads();
    }
  }

  if (t < KTOP){
    const float* bp = boxes + ((size_t)b*NBOX + sel[t])*4;
    float x1=bp[0], y1=bp[1], x2=bp[2], y2=bp[3];
    float* o = nmsbuf + ((size_t)b*KTOP + t)*6;
    o[0]=x1; o[1]=y1; o[2]=x2; o[3]=y2;
    o[4]=selsc[t];
    o[5]=fmaxf(x2-x1,0.0f)*fmaxf(y2-y1,0.0f);
  }
}

// ---------------- kernel B: single-wave register NMS + final write ----------------
__global__ __launch_bounds__(64, 1) void nms_kernel(
    const float* __restrict__ nmsbuf, const int* __restrict__ mcnt,
    float* __restrict__ out)
{
  const int b = blockIdx.x;
  const int lane = threadIdx.x;
  int Mtop = mcnt[b]; if (Mtop > KTOP) Mtop = KTOP;
  float X1[5],Y1[5],X2[5],Y2[5],AR[5],SC[5];
  unsigned keepm = 0;
  #pragma unroll
  for (int s5=0; s5<5; ++s5){
    int j = lane + 64*s5;
    if (j < KTOP){
      const float* p = nmsbuf + ((size_t)b*KTOP + j)*6;
      X1[s5]=p[0]; Y1[s5]=p[1]; X2[s5]=p[2]; Y2[s5]=p[3];
      SC[s5]=p[4]; AR[s5]=p[5];
      keepm |= (1u << s5);
    } else { X1[s5]=0;Y1[s5]=0;X2[s5]=0;Y2[s5]=0;AR[s5]=0;SC[s5]=0; }
  }
  for (int i=0;i<Mtop;i++){
    const int iw = i & 63, is = i >> 6;           // wave-uniform
    unsigned km = __shfl(keepm, iw);
    if ((km >> is) & 1u){
      float sx1 = (is==0)?X1[0]:(is==1)?X1[1]:(is==2)?X1[2]:(is==3)?X1[3]:X1[4];
      float sy1 = (is==0)?Y1[0]:(is==1)?Y1[1]:(is==2)?Y1[2]:(is==3)?Y1[3]:Y1[4];
      float sx2 = (is==0)?X2[0]:(is==1)?X2[1]:(is==2)?X2[2]:(is==3)?X2[3]:X2[4];
      float sy2 = (is==0)?Y2[0]:(is==1)?Y2[1]:(is==2)?Y2[2]:(is==3)?Y2[3]:Y2[4];
      float sa  = (is==0)?AR[0]:(is==1)?AR[1]:(is==2)?AR[2]:(is==3)?AR[3]:AR[4];
      float bx1=__shfl(sx1,iw), by1=__shfl(sy1,iw);
      float bx2=__shfl(sx2,iw), by2=__shfl(sy2,iw);
      float ba =__shfl(sa ,iw);
      #pragma unroll
      for (int s5=0; s5<5; ++s5){
        int j = lane + 64*s5;
        if (((keepm >> s5) & 1u) && j > i){
          float ix1=fmaxf(bx1,X1[s5]);
          float iy1=fmaxf(by1,Y1[s5]);
          float ix2=fminf(bx2,X2[s5]);
          float iy2=fminf(by2,Y2[s5]);
          float inter=fmaxf(ix2-ix1,0.0f)*fmaxf(iy2-iy1,0.0f);
          float iou = inter/(ba+AR[s5]-inter+1e-7f);
          if (iou > 0.5f) keepm &= ~(1u << s5);
        }
      }
    }
  }
  #pragma unroll
  for (int s5=0; s5<5; ++s5){
    int j = lane + 64*s5;
    if (j < KTOP){
      float scv = SC[s5];
      float kf  = (((keepm >> s5) & 1u) && scv > 0.0f) ? 1.0f : 0.0f;
      float* o = out + ((size_t)b*KTOP + j)*6;
      o[0]=X1[s5]; o[1]=Y1[s5]; o[2]=X2[s5]; o[3]=Y2[s5];
      o[4]=scv; o[5]=kf;
    }
  }
}

extern "C" void kernel_launch(void* const* d_in, const int* in_sizes, int n_in,
                              void* d_out, int out_size, void* d_ws, size_t ws_size,
                              hipStream_t stream) {
  const float* x  = (const float*)d_in[0];
  const float* W1 = (const float*)d_in[1];
  const float* b1 = (const float*)d_in[2];
  const float* W2 = (const float*)d_in[3];
  const float* b2 = (const float*)d_in[4];
  const float* W3 = (const float*)d_in[5];
  const float* b3 = (const float*)d_in[6];
  const float* Wh = (const float*)d_in[7];
  const float* bh = (const float*)d_in[8];
  float* out = (float*)d_out;
  float* ws  = (float*)d_ws;

  float* f1     = ws;               // 16x16x320x320 = 26,214,400
  float* f2     = ws + 26214400;    // 16x32x160x160 = 13,107,200
  float* f3     = ws;               // reuse f1: 16x64x80x80
  float* boxes  = ws + 26214400;    // reuse f2: 16x19200x4
  float* scores = boxes + 1228800;  // 16x19200
  float* nmsbuf = scores + 307200;  // 16x300x6 = 28,800
  int*   mcnt   = (int*)(nmsbuf + 28800);

  // conv1: 3->16, 640->320.  tile 64x16, C=8 (OCG=2), ICCH=3 -> 5*20*16=1600 blocks
  conv3x3s2_v3<3,16,8,3,640,320,64,16><<<5*20*BATCH, 256, 0, stream>>>(x,  W1, b1, f1);
  // conv2: 16->32, 320->160. tile 32x16, C=8 (OCG=4), ICCH=4 -> 5*10*16=800 blocks
  conv3x3s2_v3<16,32,8,4,320,160,32,16><<<5*10*BATCH, 256, 0, stream>>>(f1, W2, b2, f2);
  // conv3: 32->64, 160->80.  tile 16x16, C=8 (OCG=8), ICCH=4 -> 5*5*16=400 blocks
  conv3x3s2_v3<32,64,8,4,160,80,16,16><<<5*5*BATCH, 256, 0, stream>>>(f2, W3, b3, f3);

  decode_kernel<<<(BATCH*NANCH*GRID*GRID+255)/256, 256, 0, stream>>>(f3, Wh, bh, boxes, scores);
  topk_kernel<<<BATCH, 1024, 0, stream>>>(boxes, scores, nmsbuf, mcnt);
  nms_kernel<<<BATCH, 64, 0, stream>>>(nmsbuf, mcnt, out);
}

// Round 8
// 451.035 us; speedup vs baseline: 2.2009x; 1.2998x over previous
//
#include <hip/hip_runtime.h>
#include <math.h>

#define BATCH 16
#define GRID  80
#define NANCH 3
#define KTOP  300
#define NBOX  (NANCH*GRID*GRID)   // 19200
#define SORT_CAP 8192

__device__ __forceinline__ float sigmoidf_(float x){ return 1.0f/(1.0f+expf(-x)); }

// ---------------- 3x3 stride-2 conv + SiLU, v4 ----------------
// One block = TX x TY tile x all COUT. 256 thr = (TX/4 x TY/2) x (COUT/8).
// Row-major compute: per input row 3 b128 reads (12 regs, used immediately);
// weights wlds[icl][ky][kx][COUT] -> 2 broadcast b128 per (ky,kx).
// LDS bank swizzle: +4 dwords per odd row-group so b128 bases cover all 8
// tetrads (conflict floor). Summation order (ic,ky,kx) == reference chain.
template<int CIN,int COUT,int ICCH,int HIN,int HOUT,int TX,int TY>
__global__ __launch_bounds__(256, 1) void conv3x3s2_v4(
    const float* __restrict__ in, const float* __restrict__ w,
    const float* __restrict__ bias, float* __restrict__ out)
{
  constexpr int NTX = TX/4, NTY = TY/2, NSP = NTX*NTY, OCG = COUT/8;
  static_assert(NSP*OCG == 256, "bad thread layout");
  constexpr int HR = 2*TY+1, HC = 2*TX+1;
  constexpr int NB4  = HC/4;                  // full float4 groups per row
  constexpr int PADC = ((HC+3)/4)*4 + 4;      // row stride + swizzle room
  constexpr int ILDSC = HR*PADC;
  constexpr int TBX = HOUT/TX, TBY = HOUT/TY;
  static_assert(TBX*TX == HOUT && TBY*TY == HOUT, "no masking");
  __shared__ float ilds[ICCH*ILDSC];
  __shared__ float wlds[ICCH*9*COUT];

  const int t  = threadIdx.x;
  const int sx = t % NTX;
  const int sy = (t / NTX) % NTY;
  const int og = t / NSP;                     // high bits -> wave-uniform
  int blk = blockIdx.x;
  const int bx = blk % TBX; blk /= TBX;
  const int by = blk % TBY; blk /= TBY;
  const int b  = blk;

  const int ix0 = bx*2*TX, iy0 = by*2*TY;
  const int ylim = (iy0 + HR <= HIN) ? HR : (HIN - iy0);
  const bool tail_ok = (ix0 + NB4*4 < HIN);

  float acc[8][2][4];
  #pragma unroll
  for (int j=0;j<8;++j){
    float bv = bias[og*8+j];
    #pragma unroll
    for (int py=0;py<2;++py)
      #pragma unroll
      for (int px=0;px<4;++px) acc[j][py][px]=bv;
  }

  for (int c0=0; c0<CIN; c0+=ICCH){
    __syncthreads();
    // ---- stage input halo: masked float4 loads -> b128 LDS writes
    #pragma unroll 1
    for (int c=0;c<ICCH;++c){
      const float* gp = in + (size_t)(b*CIN + c0 + c)*HIN*HIN;
      float* lp = ilds + c*ILDSC;
      for (int i=t; i<HR*NB4; i+=256){
        int r = i/NB4, m = i - r*NB4;
        float4 v = make_float4(0.f,0.f,0.f,0.f);
        if (r < ylim) v = *(const float4*)(gp + (size_t)(iy0+r)*HIN + ix0 + 4*m);
        *(float4*)(lp + r*PADC + 4*((r>>2)&1) + 4*m) = v;
      }
      for (int r=t; r<HR; r+=256){
        float v = 0.0f;
        if (r < ylim && tail_ok) v = gp[(size_t)(iy0+r)*HIN + ix0 + NB4*4];
        lp[r*PADC + 4*((r>>2)&1) + NB4*4] = v;
      }
    }
    // ---- stage weights: wlds[((icl*3+ky)*3+kx)*COUT + oc]
    for (int i=t; i<ICCH*9*COUT; i+=256){
      int oc  = i % COUT;
      int k   = (i / COUT) % 9;
      int icl = i / (9*COUT);
      wlds[i] = w[((size_t)oc*CIN + c0+icl)*9 + k];
    }
    __syncthreads();

    #pragma unroll 1
    for (int icl=0; icl<ICCH; ++icl){
      const float* ipb = ilds + icl*ILDSC + 8*sx;
      const float* wpb = wlds + icl*9*COUT + og*8;
      #pragma unroll
      for (int r=0;r<5;++r){
        const int rr = 4*sy + r;
        const float* rp = ipb + rr*PADC + 4*((rr>>2)&1);
        float rw[12];
        #pragma unroll
        for (int m=0;m<3;++m){
          float4 v4 = *(const float4*)(rp + 4*m);
          rw[4*m+0]=v4.x; rw[4*m+1]=v4.y; rw[4*m+2]=v4.z; rw[4*m+3]=v4.w;
        }
        #pragma unroll
        for (int py=0;py<2;++py){
          const int ky = r - 2*py;
          if (ky >= 0 && ky < 3){
            #pragma unroll
            for (int kx=0;kx<3;++kx){
              const float4 wa = *(const float4*)(wpb + (ky*3+kx)*COUT);
              const float4 wb = *(const float4*)(wpb + (ky*3+kx)*COUT + 4);
              #pragma unroll
              for (int px=0;px<4;++px){
                const float xv = rw[2*px+kx];
                acc[0][py][px] += xv*wa.x; acc[1][py][px] += xv*wa.y;
                acc[2][py][px] += xv*wa.z; acc[3][py][px] += xv*wa.w;
                acc[4][py][px] += xv*wb.x; acc[5][py][px] += xv*wb.y;
                acc[6][py][px] += xv*wb.z; acc[7][py][px] += xv*wb.w;
              }
            }
          }
        }
      }
    }
  }

  // ---- epilogue: SiLU + float4 stores
  const int oxb = bx*TX + sx*4;
  #pragma unroll
  for (int j=0;j<8;++j){
    int oc = og*8+j;
    #pragma unroll
    for (int py=0;py<2;++py){
      int oy = by*TY + sy*2 + py;
      float4 o4;
      float z0=acc[j][py][0], z1=acc[j][py][1], z2=acc[j][py][2], z3=acc[j][py][3];
      o4.x = z0/(1.0f+expf(-z0));
      o4.y = z1/(1.0f+expf(-z1));
      o4.z = z2/(1.0f+expf(-z2));
      o4.w = z3/(1.0f+expf(-z3));
      *(float4*)(out + ((size_t)(b*COUT+oc)*HOUT + oy)*HOUT + oxb) = o4;
    }
  }
}

// ---------------- 1x1 head (6 needed channels) + sigmoid + decode ----------------
__global__ __launch_bounds__(256) void decode_kernel(
    const float* __restrict__ f3, const float* __restrict__ Wh,
    const float* __restrict__ bh, float* __restrict__ boxes,
    float* __restrict__ scores)
{
  int idx = blockIdx.x*256 + threadIdx.x;
  const int total = BATCH*NANCH*GRID*GRID;
  if (idx >= total) return;
  int gx = idx % GRID;
  int gy = (idx/GRID)%GRID;
  int a  = (idx/(GRID*GRID))%NANCH;
  int b  = idx/(GRID*GRID*NANCH);
  const float aw[3] = {4.0f, 8.0f, 13.0f};
  const float ah[3] = {5.0f, 10.0f, 16.0f};
  const int   chs[6] = {0,1,2,3,4,15};
  const float* f = f3 + (size_t)b*64*GRID*GRID + (size_t)gy*GRID + gx;
  float acc[6];
  #pragma unroll
  for (int j=0;j<6;j++) acc[j] = bh[a*16 + chs[j]];
  for (int ic=0; ic<64; ++ic){
    float v = f[(size_t)ic*GRID*GRID];
    #pragma unroll
    for (int j=0;j<6;j++) acc[j] += v * Wh[(size_t)(a*16+chs[j])*64 + ic];
  }
  float p0 = sigmoidf_(acc[0]);
  float p1 = sigmoidf_(acc[1]);
  float p2 = sigmoidf_(acc[2]);
  float p3 = sigmoidf_(acc[3]);
  float p4 = sigmoidf_(acc[4]);
  float p15= sigmoidf_(acc[5]);
  float cx = (p0*2.0f - 0.5f + (float)gx)*8.0f;
  float cy = (p1*2.0f - 0.5f + (float)gy)*8.0f;
  float ww = p2*2.0f; ww = ww*ww*aw[a];
  float hh = p3*2.0f; hh = hh*hh*ah[a];
  float sc = p4*p15;
  sc = (sc > 0.5f) ? sc : 0.0f;
  int bi = a*GRID*GRID + gy*GRID + gx;
  float* bo = boxes + ((size_t)b*NBOX + bi)*4;
  bo[0] = cx - ww*0.5f;
  bo[1] = cy - hh*0.5f;
  bo[2] = cx + ww*0.5f;
  bo[3] = cy + hh*0.5f;
  scores[(size_t)b*NBOX + bi] = sc;
}

// ---------------- kernel A: compact + bitonic-sort top-K + gather ----------------
__global__ __launch_bounds__(1024) void topk_kernel(
    const float* __restrict__ boxes, const float* __restrict__ scores,
    float* __restrict__ nmsbuf, int* __restrict__ mcnt)
{
  __shared__ unsigned long long keys[SORT_CAP];  // 64 KB
  __shared__ int   cntM;
  __shared__ int   sel[KTOP];
  __shared__ float selsc[KTOP];
  __shared__ int   wsum[16];
  __shared__ float rs[16];
  __shared__ int   ri[16];
  __shared__ unsigned clm[(NBOX+31)/32];         // fallback claimed bitmask

  const int b = blockIdx.x;
  const int t = threadIdx.x;
  const int lane = t & 63, wv = t >> 6;
  const float* scp = scores + (size_t)b*NBOX;

  if (t == 0) cntM = 0;
  __syncthreads();

  for (int i=t; i<NBOX; i+=1024){
    float v = scp[i];
    if (v > 0.0f){
      int p = atomicAdd(&cntM, 1);
      if (p < SORT_CAP)
        keys[p] = ((unsigned long long)__float_as_uint(v) << 32)
                | (unsigned)(0xFFFFFFFFu - (unsigned)i);
    }
  }
  __syncthreads();
  const int M = cntM;
  if (t == 0) mcnt[b] = M;

  if (M <= SORT_CAP){
    int P = 64; while (P < M) P <<= 1;
    for (int i=t; i<P; i+=1024) if (i >= M) keys[i] = 0ULL;
    __syncthreads();
    for (int k=2; k<=P; k<<=1){
      for (int j=k>>1; j>0; j>>=1){
        for (int i=t; i<P; i+=1024){
          int ixj = i ^ j;
          if (ixj > i){
            unsigned long long a = keys[i], c = keys[ixj];
            bool up = ((i & k) == 0);
            if (up ? (a < c) : (a > c)){ keys[i] = c; keys[ixj] = a; }
          }
        }
        __syncthreads();
      }
    }
    const int top = (M < KTOP) ? M : KTOP;
    if (t < top){
      unsigned long long kk = keys[t];
      selsc[t] = __uint_as_float((unsigned)(kk >> 32));
      sel[t]   = (int)(0xFFFFFFFFu - (unsigned)(kk & 0xFFFFFFFFu));
    }
    if (M < KTOP){
      const int need = KTOP - M;
      const int C = (NBOX + 1023)/1024;   // 19
      int lo = t*C, hi = lo+C; if (hi > NBOX) hi = NBOX; if (lo > NBOX) lo = NBOX;
      int zc = 0;
      for (int i=lo;i<hi;i++) if (scp[i] <= 0.0f) zc++;
      int v = zc;
      #pragma unroll
      for (int off=1; off<64; off<<=1){
        int n = __shfl_up(v, off);
        if (lane >= off) v += n;
      }
      if (lane == 63) wsum[wv] = v;
      __syncthreads();
      if (t == 0){
        int a = 0;
        for (int w=0; w<16; w++){ int tmp = wsum[w]; wsum[w] = a; a += tmp; }
      }
      __syncthreads();
      int r = wsum[wv] + v - zc;
      for (int i=lo;i<hi;i++){
        if (scp[i] <= 0.0f){
          if (r < need){ sel[M+r] = i; selsc[M+r] = 0.0f; }
          r++;
        }
      }
    }
    __syncthreads();
  } else {
    for (int i=t; i<(NBOX+31)/32; i+=1024) clm[i] = 0u;
    __syncthreads();
    for (int k=0;k<KTOP;k++){
      float best = -2.0f; int bi = NBOX;
      for (int i=t;i<NBOX;i+=1024){
        if (!((clm[i>>5] >> (i&31)) & 1u)){
          float v = scp[i];
          if (v > best){ best=v; bi=i; }
        }
      }
      #pragma unroll
      for (int off=32; off>0; off>>=1){
        float ov = __shfl_down(best, off);
        int   oi = __shfl_down(bi,   off);
        if (ov > best || (ov == best && oi < bi)){ best=ov; bi=oi; }
      }
      if (lane == 0){ rs[wv]=best; ri[wv]=bi; }
      __syncthreads();
      if (t == 0){
        for (int w=1; w<16; w++)
          if (rs[w] > best || (rs[w] == best && ri[w] < bi)){ best=rs[w]; bi=ri[w]; }
        sel[k]=bi; selsc[k]=best; clm[bi>>5] |= (1u << (bi&31));
      }
      __syncthreads();
    }
  }

  if (t < KTOP){
    const float* bp = boxes + ((size_t)b*NBOX + sel[t])*4;
    float x1=bp[0], y1=bp[1], x2=bp[2], y2=bp[3];
    float* o = nmsbuf + ((size_t)b*KTOP + t)*6;
    o[0]=x1; o[1]=y1; o[2]=x2; o[3]=y2;
    o[4]=selsc[t];
    o[5]=fmaxf(x2-x1,0.0f)*fmaxf(y2-y1,0.0f);
  }
}

// ---------------- kernel B: single-wave register NMS + final write ----------------
__global__ __launch_bounds__(64, 1) void nms_kernel(
    const float* __restrict__ nmsbuf, const int* __restrict__ mcnt,
    float* __restrict__ out)
{
  const int b = blockIdx.x;
  const int lane = threadIdx.x;
  int Mtop = mcnt[b]; if (Mtop > KTOP) Mtop = KTOP;
  float X1[5],Y1[5],X2[5],Y2[5],AR[5],SC[5];
  unsigned keepm = 0;
  #pragma unroll
  for (int s5=0; s5<5; ++s5){
    int j = lane + 64*s5;
    if (j < KTOP){
      const float* p = nmsbuf + ((size_t)b*KTOP + j)*6;
      X1[s5]=p[0]; Y1[s5]=p[1]; X2[s5]=p[2]; Y2[s5]=p[3];
      SC[s5]=p[4]; AR[s5]=p[5];
      keepm |= (1u << s5);
    } else { X1[s5]=0;Y1[s5]=0;X2[s5]=0;Y2[s5]=0;AR[s5]=0;SC[s5]=0; }
  }
  for (int i=0;i<Mtop;i++){
    const int iw = i & 63, is = i >> 6;           // wave-uniform
    unsigned km = __shfl(keepm, iw);
    if ((km >> is) & 1u){
      float sx1 = (is==0)?X1[0]:(is==1)?X1[1]:(is==2)?X1[2]:(is==3)?X1[3]:X1[4];
      float sy1 = (is==0)?Y1[0]:(is==1)?Y1[1]:(is==2)?Y1[2]:(is==3)?Y1[3]:Y1[4];
      float sx2 = (is==0)?X2[0]:(is==1)?X2[1]:(is==2)?X2[2]:(is==3)?X2[3]:X2[4];
      float sy2 = (is==0)?Y2[0]:(is==1)?Y2[1]:(is==2)?Y2[2]:(is==3)?Y2[3]:Y2[4];
      float sa  = (is==0)?AR[0]:(is==1)?AR[1]:(is==2)?AR[2]:(is==3)?AR[3]:AR[4];
      float bx1=__shfl(sx1,iw), by1=__shfl(sy1,iw);
      float bx2=__shfl(sx2,iw), by2=__shfl(sy2,iw);
      float ba =__shfl(sa ,iw);
      #pragma unroll
      for (int s5=0; s5<5; ++s5){
        int j = lane + 64*s5;
        if (((keepm >> s5) & 1u) && j > i){
          float ix1=fmaxf(bx1,X1[s5]);
          float iy1=fmaxf(by1,Y1[s5]);
          float ix2=fminf(bx2,X2[s5]);
          float iy2=fminf(by2,Y2[s5]);
          float inter=fmaxf(ix2-ix1,0.0f)*fmaxf(iy2-iy1,0.0f);
          float iou = inter/(ba+AR[s5]-inter+1e-7f);
          if (iou > 0.5f) keepm &= ~(1u << s5);
        }
      }
    }
  }
  #pragma unroll
  for (int s5=0; s5<5; ++s5){
    int j = lane + 64*s5;
    if (j < KTOP){
      float scv = SC[s5];
      float kf  = (((keepm >> s5) & 1u) && scv > 0.0f) ? 1.0f : 0.0f;
      float* o = out + ((size_t)b*KTOP + j)*6;
      o[0]=X1[s5]; o[1]=Y1[s5]; o[2]=X2[s5]; o[3]=Y2[s5];
      o[4]=scv; o[5]=kf;
    }
  }
}

extern "C" void kernel_launch(void* const* d_in, const int* in_sizes, int n_in,
                              void* d_out, int out_size, void* d_ws, size_t ws_size,
                              hipStream_t stream) {
  const float* x  = (const float*)d_in[0];
  const float* W1 = (const float*)d_in[1];
  const float* b1 = (const float*)d_in[2];
  const float* W2 = (const float*)d_in[3];
  const float* b2 = (const float*)d_in[4];
  const float* W3 = (const float*)d_in[5];
  const float* b3 = (const float*)d_in[6];
  const float* Wh = (const float*)d_in[7];
  const float* bh = (const float*)d_in[8];
  float* out = (float*)d_out;
  float* ws  = (float*)d_ws;

  float* f1     = ws;               // 16x16x320x320 = 26,214,400
  float* f2     = ws + 26214400;    // 16x32x160x160 = 13,107,200
  float* f3     = ws;               // reuse f1: 16x64x80x80
  float* boxes  = ws + 26214400;    // reuse f2: 16x19200x4
  float* scores = boxes + 1228800;  // 16x19200
  float* nmsbuf = scores + 307200;  // 16x300x6 = 28,800
  int*   mcnt   = (int*)(nmsbuf + 28800);

  // conv1: 3->16, 640->320.  tile 64x16, OCG=2, ICCH=3 -> 1600 blocks
  conv3x3s2_v4<3,16,3,640,320,64,16><<<5*20*BATCH, 256, 0, stream>>>(x,  W1, b1, f1);
  // conv2: 16->32, 320->160. tile 32x16, OCG=4, ICCH=4 -> 800 blocks
  conv3x3s2_v4<16,32,4,320,160,32,16><<<5*10*BATCH, 256, 0, stream>>>(f1, W2, b2, f2);
  // conv3: 32->64, 160->80.  tile 16x16, OCG=8, ICCH=4 -> 400 blocks
  conv3x3s2_v4<32,64,4,160,80,16,16><<<5*5*BATCH, 256, 0, stream>>>(f2, W3, b3, f3);

  decode_kernel<<<(BATCH*NANCH*GRID*GRID+255)/256, 256, 0, stream>>>(f3, Wh, bh, boxes, scores);
  topk_kernel<<<BATCH, 1024, 0, stream>>>(boxes, scores, nmsbuf, mcnt);
  nms_kernel<<<BATCH, 64, 0, stream>>>(nmsbuf, mcnt, out);
}

// Round 9
// 440.531 us; speedup vs baseline: 2.2534x; 1.0238x over previous
//
#include <hip/hip_runtime.h>
#include <math.h>

#define BATCH 16
#define GRID  80
#define NANCH 3
#define KTOP  300
#define NBOX  (NANCH*GRID*GRID)   // 19200
#define SORT_CAP 8192

__device__ __forceinline__ float sigmoidf_(float x){ return 1.0f/(1.0f+expf(-x)); }

// ---------------- 3x3 stride-2 conv + SiLU, v5 ----------------
// One block = TX x TY tile x all COUT. 256 thr = (TX/4 x TY/2) x (COUT/C).
// v5: small ICCH -> small LDS -> 7-8 blocks/CU co-resident (latency hiding via
// TLP); staging flattened over (c,r,quad) for full-width load issue.
// Summation order per acc: ic asc, ky asc, kx asc (bit-exact vs reference).
template<int CIN,int COUT,int C,int ICCH,int HIN,int HOUT,int TX,int TY>
__global__ __launch_bounds__(256, 1) void conv3x3s2_v5(
    const float* __restrict__ in, const float* __restrict__ w,
    const float* __restrict__ bias, float* __restrict__ out)
{
  constexpr int NTX = TX/4, NTY = TY/2, NSP = NTX*NTY, OCG = COUT/C;
  static_assert(NSP*OCG == 256, "bad thread layout");
  static_assert(C==4 || C==8, "C must be 4 or 8");
  constexpr int HR = 2*TY+1, HC = 2*TX+1;
  constexpr int NB4  = HC/4;                  // full float4 groups per row
  constexpr int PADC = ((HC+3)/4)*4 + 4;      // row stride + swizzle room
  constexpr int ILDSC = HR*PADC;
  constexpr int TBX = HOUT/TX, TBY = HOUT/TY;
  static_assert(TBX*TX == HOUT && TBY*TY == HOUT, "no masking");
  __shared__ float ilds[ICCH*ILDSC];
  __shared__ float wlds[ICCH*9*COUT];

  const int t  = threadIdx.x;
  const int sx = t % NTX;
  const int sy = (t / NTX) % NTY;
  const int og = t / NSP;
  int blk = blockIdx.x;
  const int bx = blk % TBX; blk /= TBX;
  const int by = blk % TBY; blk /= TBY;
  const int b  = blk;

  const int ix0 = bx*2*TX, iy0 = by*2*TY;
  const int ylim = (iy0 + HR <= HIN) ? HR : (HIN - iy0);
  const bool tail_ok = (ix0 + NB4*4 < HIN);

  float acc[C][2][4];
  #pragma unroll
  for (int j=0;j<C;++j){
    float bv = bias[og*C+j];
    #pragma unroll
    for (int py=0;py<2;++py)
      #pragma unroll
      for (int px=0;px<4;++px) acc[j][py][px]=bv;
  }

  for (int c0=0; c0<CIN; c0+=ICCH){
    __syncthreads();
    // ---- stage input halo, flat over (c, r, quad): full-width load issue
    for (int i=t; i<ICCH*HR*NB4; i+=256){
      int c = i/(HR*NB4), rm = i - c*(HR*NB4);
      int r = rm/NB4, m = rm - r*NB4;
      float4 v = make_float4(0.f,0.f,0.f,0.f);
      if (r < ylim)
        v = *(const float4*)(in + (size_t)(b*CIN + c0 + c)*HIN*HIN
                                + (size_t)(iy0+r)*HIN + ix0 + 4*m);
      *(float4*)(ilds + c*ILDSC + r*PADC + 4*((r>>2)&1) + 4*m) = v;
    }
    for (int i=t; i<ICCH*HR; i+=256){
      int c = i/HR, r = i - c*HR;
      float v = 0.0f;
      if (r < ylim && tail_ok)
        v = in[(size_t)(b*CIN + c0 + c)*HIN*HIN + (size_t)(iy0+r)*HIN + ix0 + NB4*4];
      ilds[c*ILDSC + r*PADC + 4*((r>>2)&1) + NB4*4] = v;
    }
    // ---- stage weights: wlds[((icl*3+ky)*3+kx)*COUT + oc]
    for (int i=t; i<ICCH*9*COUT; i+=256){
      int oc  = i % COUT;
      int k   = (i / COUT) % 9;
      int icl = i / (9*COUT);
      wlds[i] = w[((size_t)oc*CIN + c0+icl)*9 + k];
    }
    __syncthreads();

    #pragma unroll 1
    for (int icl=0; icl<ICCH; ++icl){
      const float* ipb = ilds + icl*ILDSC + 8*sx;
      const float* wpb = wlds + icl*9*COUT + og*C;
      #pragma unroll
      for (int r=0;r<5;++r){
        const int rr = 4*sy + r;
        const float* rp = ipb + rr*PADC + 4*((rr>>2)&1);
        float rw[12];
        #pragma unroll
        for (int m=0;m<3;++m){
          float4 v4 = *(const float4*)(rp + 4*m);
          rw[4*m+0]=v4.x; rw[4*m+1]=v4.y; rw[4*m+2]=v4.z; rw[4*m+3]=v4.w;
        }
        #pragma unroll
        for (int py=0;py<2;++py){
          const int ky = r - 2*py;
          if (ky >= 0 && ky < 3){
            #pragma unroll
            for (int kx=0;kx<3;++kx){
              const float4 wa = *(const float4*)(wpb + (ky*3+kx)*COUT);
              #pragma unroll
              for (int px=0;px<4;++px){
                const float xv = rw[2*px+kx];
                acc[0][py][px] += xv*wa.x; acc[1][py][px] += xv*wa.y;
                acc[2][py][px] += xv*wa.z; acc[3][py][px] += xv*wa.w;
              }
              if constexpr (C==8){
                const float4 wb = *(const float4*)(wpb + (ky*3+kx)*COUT + 4);
                #pragma unroll
                for (int px=0;px<4;++px){
                  const float xv = rw[2*px+kx];
                  acc[4][py][px] += xv*wb.x; acc[5][py][px] += xv*wb.y;
                  acc[6][py][px] += xv*wb.z; acc[7][py][px] += xv*wb.w;
                }
              }
            }
          }
        }
      }
    }
  }

  // ---- epilogue: SiLU + float4 stores
  const int oxb = bx*TX + sx*4;
  #pragma unroll
  for (int j=0;j<C;++j){
    int oc = og*C+j;
    #pragma unroll
    for (int py=0;py<2;++py){
      int oy = by*TY + sy*2 + py;
      float4 o4;
      float z0=acc[j][py][0], z1=acc[j][py][1], z2=acc[j][py][2], z3=acc[j][py][3];
      o4.x = z0/(1.0f+expf(-z0));
      o4.y = z1/(1.0f+expf(-z1));
      o4.z = z2/(1.0f+expf(-z2));
      o4.w = z3/(1.0f+expf(-z3));
      *(float4*)(out + ((size_t)(b*COUT+oc)*HOUT + oy)*HOUT + oxb) = o4;
    }
  }
}

// ---------------- 1x1 head (6 needed channels) + sigmoid + decode ----------------
__global__ __launch_bounds__(256) void decode_kernel(
    const float* __restrict__ f3, const float* __restrict__ Wh,
    const float* __restrict__ bh, float* __restrict__ boxes,
    float* __restrict__ scores)
{
  int idx = blockIdx.x*256 + threadIdx.x;
  const int total = BATCH*NANCH*GRID*GRID;
  if (idx >= total) return;
  int gx = idx % GRID;
  int gy = (idx/GRID)%GRID;
  int a  = (idx/(GRID*GRID))%NANCH;
  int b  = idx/(GRID*GRID*NANCH);
  const float aw[3] = {4.0f, 8.0f, 13.0f};
  const float ah[3] = {5.0f, 10.0f, 16.0f};
  const int   chs[6] = {0,1,2,3,4,15};
  const float* f = f3 + (size_t)b*64*GRID*GRID + (size_t)gy*GRID + gx;
  float acc[6];
  #pragma unroll
  for (int j=0;j<6;j++) acc[j] = bh[a*16 + chs[j]];
  for (int ic=0; ic<64; ++ic){
    float v = f[(size_t)ic*GRID*GRID];
    #pragma unroll
    for (int j=0;j<6;j++) acc[j] += v * Wh[(size_t)(a*16+chs[j])*64 + ic];
  }
  float p0 = sigmoidf_(acc[0]);
  float p1 = sigmoidf_(acc[1]);
  float p2 = sigmoidf_(acc[2]);
  float p3 = sigmoidf_(acc[3]);
  float p4 = sigmoidf_(acc[4]);
  float p15= sigmoidf_(acc[5]);
  float cx = (p0*2.0f - 0.5f + (float)gx)*8.0f;
  float cy = (p1*2.0f - 0.5f + (float)gy)*8.0f;
  float ww = p2*2.0f; ww = ww*ww*aw[a];
  float hh = p3*2.0f; hh = hh*hh*ah[a];
  float sc = p4*p15;
  sc = (sc > 0.5f) ? sc : 0.0f;
  int bi = a*GRID*GRID + gy*GRID + gx;
  float* bo = boxes + ((size_t)b*NBOX + bi)*4;
  bo[0] = cx - ww*0.5f;
  bo[1] = cy - hh*0.5f;
  bo[2] = cx + ww*0.5f;
  bo[3] = cy + hh*0.5f;
  scores[(size_t)b*NBOX + bi] = sc;
}

// ---------------- kernel A: compact + bitonic-sort top-K + gather ----------------
__global__ __launch_bounds__(1024) void topk_kernel(
    const float* __restrict__ boxes, const float* __restrict__ scores,
    float* __restrict__ nmsbuf, int* __restrict__ mcnt)
{
  __shared__ unsigned long long keys[SORT_CAP];  // 64 KB
  __shared__ int   cntM;
  __shared__ int   sel[KTOP];
  __shared__ float selsc[KTOP];
  __shared__ int   wsum[16];
  __shared__ float rs[16];
  __shared__ int   ri[16];
  __shared__ unsigned clm[(NBOX+31)/32];         // fallback claimed bitmask

  const int b = blockIdx.x;
  const int t = threadIdx.x;
  const int lane = t & 63, wv = t >> 6;
  const float* scp = scores + (size_t)b*NBOX;

  if (t == 0) cntM = 0;
  __syncthreads();

  for (int i=t; i<NBOX; i+=1024){
    float v = scp[i];
    if (v > 0.0f){
      int p = atomicAdd(&cntM, 1);
      if (p < SORT_CAP)
        keys[p] = ((unsigned long long)__float_as_uint(v) << 32)
                | (unsigned)(0xFFFFFFFFu - (unsigned)i);
    }
  }
  __syncthreads();
  const int M = cntM;
  if (t == 0) mcnt[b] = M;

  if (M <= SORT_CAP){
    int P = 64; while (P < M) P <<= 1;
    for (int i=t; i<P; i+=1024) if (i >= M) keys[i] = 0ULL;
    __syncthreads();
    for (int k=2; k<=P; k<<=1){
      for (int j=k>>1; j>0; j>>=1){
        for (int i=t; i<P; i+=1024){
          int ixj = i ^ j;
          if (ixj > i){
            unsigned long long a = keys[i], c = keys[ixj];
            bool up = ((i & k) == 0);
            if (up ? (a < c) : (a > c)){ keys[i] = c; keys[ixj] = a; }
          }
        }
        __syncthreads();
      }
    }
    const int top = (M < KTOP) ? M : KTOP;
    if (t < top){
      unsigned long long kk = keys[t];
      selsc[t] = __uint_as_float((unsigned)(kk >> 32));
      sel[t]   = (int)(0xFFFFFFFFu - (unsigned)(kk & 0xFFFFFFFFu));
    }
    if (M < KTOP){
      const int need = KTOP - M;
      const int C = (NBOX + 1023)/1024;   // 19
      int lo = t*C, hi = lo+C; if (hi > NBOX) hi = NBOX; if (lo > NBOX) lo = NBOX;
      int zc = 0;
      for (int i=lo;i<hi;i++) if (scp[i] <= 0.0f) zc++;
      int v = zc;
      #pragma unroll
      for (int off=1; off<64; off<<=1){
        int n = __shfl_up(v, off);
        if (lane >= off) v += n;
      }
      if (lane == 63) wsum[wv] = v;
      __syncthreads();
      if (t == 0){
        int a = 0;
        for (int w=0; w<16; w++){ int tmp = wsum[w]; wsum[w] = a; a += tmp; }
      }
      __syncthreads();
      int r = wsum[wv] + v - zc;
      for (int i=lo;i<hi;i++){
        if (scp[i] <= 0.0f){
          if (r < need){ sel[M+r] = i; selsc[M+r] = 0.0f; }
          r++;
        }
      }
    }
    __syncthreads();
  } else {
    for (int i=t; i<(NBOX+31)/32; i+=1024) clm[i] = 0u;
    __syncthreads();
    for (int k=0;k<KTOP;k++){
      float best = -2.0f; int bi = NBOX;
      for (int i=t;i<NBOX;i+=1024){
        if (!((clm[i>>5] >> (i&31)) & 1u)){
          float v = scp[i];
          if (v > best){ best=v; bi=i; }
        }
      }
      #pragma unroll
      for (int off=32; off>0; off>>=1){
        float ov = __shfl_down(best, off);
        int   oi = __shfl_down(bi,   off);
        if (ov > best || (ov == best && oi < bi)){ best=ov; bi=oi; }
      }
      if (lane == 0){ rs[wv]=best; ri[wv]=bi; }
      __syncthreads();
      if (t == 0){
        for (int w=1; w<16; w++)
          if (rs[w] > best || (rs[w] == best && ri[w] < bi)){ best=rs[w]; bi=ri[w]; }
        sel[k]=bi; selsc[k]=best; clm[bi>>5] |= (1u << (bi&31));
      }
      __syncthreads();
    }
  }

  if (t < KTOP){
    const float* bp = boxes + ((size_t)b*NBOX + sel[t])*4;
    float x1=bp[0], y1=bp[1], x2=bp[2], y2=bp[3];
    float* o = nmsbuf + ((size_t)b*KTOP + t)*6;
    o[0]=x1; o[1]=y1; o[2]=x2; o[3]=y2;
    o[4]=selsc[t];
    o[5]=fmaxf(x2-x1,0.0f)*fmaxf(y2-y1,0.0f);
  }
}

// ---------------- kernel B: single-wave register NMS + final write ----------------
__global__ __launch_bounds__(64, 1) void nms_kernel(
    const float* __restrict__ nmsbuf, const int* __restrict__ mcnt,
    float* __restrict__ out)
{
  const int b = blockIdx.x;
  const int lane = threadIdx.x;
  int Mtop = mcnt[b]; if (Mtop > KTOP) Mtop = KTOP;
  float X1[5],Y1[5],X2[5],Y2[5],AR[5],SC[5];
  unsigned keepm = 0;
  #pragma unroll
  for (int s5=0; s5<5; ++s5){
    int j = lane + 64*s5;
    if (j < KTOP){
      const float* p = nmsbuf + ((size_t)b*KTOP + j)*6;
      X1[s5]=p[0]; Y1[s5]=p[1]; X2[s5]=p[2]; Y2[s5]=p[3];
      SC[s5]=p[4]; AR[s5]=p[5];
      keepm |= (1u << s5);
    } else { X1[s5]=0;Y1[s5]=0;X2[s5]=0;Y2[s5]=0;AR[s5]=0;SC[s5]=0; }
  }
  for (int i=0;i<Mtop;i++){
    const int iw = i & 63, is = i >> 6;           // wave-uniform
    unsigned km = __shfl(keepm, iw);
    if ((km >> is) & 1u){
      float sx1 = (is==0)?X1[0]:(is==1)?X1[1]:(is==2)?X1[2]:(is==3)?X1[3]:X1[4];
      float sy1 = (is==0)?Y1[0]:(is==1)?Y1[1]:(is==2)?Y1[2]:(is==3)?Y1[3]:Y1[4];
      float sx2 = (is==0)?X2[0]:(is==1)?X2[1]:(is==2)?X2[2]:(is==3)?X2[3]:X2[4];
      float sy2 = (is==0)?Y2[0]:(is==1)?Y2[1]:(is==2)?Y2[2]:(is==3)?Y2[3]:Y2[4];
      float sa  = (is==0)?AR[0]:(is==1)?AR[1]:(is==2)?AR[2]:(is==3)?AR[3]:AR[4];
      float bx1=__shfl(sx1,iw), by1=__shfl(sy1,iw);
      float bx2=__shfl(sx2,iw), by2=__shfl(sy2,iw);
      float ba =__shfl(sa ,iw);
      #pragma unroll
      for (int s5=0; s5<5; ++s5){
        int j = lane + 64*s5;
        if (((keepm >> s5) & 1u) && j > i){
          float ix1=fmaxf(bx1,X1[s5]);
          float iy1=fmaxf(by1,Y1[s5]);
          float ix2=fminf(bx2,X2[s5]);
          float iy2=fminf(by2,Y2[s5]);
          float inter=fmaxf(ix2-ix1,0.0f)*fmaxf(iy2-iy1,0.0f);
          float iou = inter/(ba+AR[s5]-inter+1e-7f);
          if (iou > 0.5f) keepm &= ~(1u << s5);
        }
      }
    }
  }
  #pragma unroll
  for (int s5=0; s5<5; ++s5){
    int j = lane + 64*s5;
    if (j < KTOP){
      float scv = SC[s5];
      float kf  = (((keepm >> s5) & 1u) && scv > 0.0f) ? 1.0f : 0.0f;
      float* o = out + ((size_t)b*KTOP + j)*6;
      o[0]=X1[s5]; o[1]=Y1[s5]; o[2]=X2[s5]; o[3]=Y2[s5];
      o[4]=scv; o[5]=kf;
    }
  }
}

extern "C" void kernel_launch(void* const* d_in, const int* in_sizes, int n_in,
                              void* d_out, int out_size, void* d_ws, size_t ws_size,
                              hipStream_t stream) {
  const float* x  = (const float*)d_in[0];
  const float* W1 = (const float*)d_in[1];
  const float* b1 = (const float*)d_in[2];
  const float* W2 = (const float*)d_in[3];
  const float* b2 = (const float*)d_in[4];
  const float* W3 = (const float*)d_in[5];
  const float* b3 = (const float*)d_in[6];
  const float* Wh = (const float*)d_in[7];
  const float* bh = (const float*)d_in[8];
  float* out = (float*)d_out;
  float* ws  = (float*)d_ws;

  float* f1     = ws;               // 16x16x320x320 = 26,214,400
  float* f2     = ws + 26214400;    // 16x32x160x160 = 13,107,200
  float* f3     = ws;               // reuse f1: 16x64x80x80
  float* boxes  = ws + 26214400;    // reuse f2: 16x19200x4
  float* scores = boxes + 1228800;  // 16x19200
  float* nmsbuf = scores + 307200;  // 16x300x6 = 28,800
  int*   mcnt   = (int*)(nmsbuf + 28800);

  // conv1: 3->16, tile 64x16, C=8, ICCH=1 -> ~18.6 KB LDS, 1600 blocks
  conv3x3s2_v5<3,16,8,1,640,320,64,16><<<5*20*BATCH, 256, 0, stream>>>(x,  W1, b1, f1);
  // conv2: 16->32, tile 32x16, C=8, ICCH=2 -> ~21.4 KB LDS, 800 blocks
  conv3x3s2_v5<16,32,8,2,320,160,32,16><<<5*10*BATCH, 256, 0, stream>>>(f1, W2, b2, f2);
  // conv3: 32->64, tile 16x8, C=4, ICCH=4 -> ~20 KB LDS, 800 blocks
  conv3x3s2_v5<32,64,4,4,160,80,16,8><<<5*10*BATCH, 256, 0, stream>>>(f2, W3, b3, f3);

  decode_kernel<<<(BATCH*NANCH*GRID*GRID+255)/256, 256, 0, stream>>>(f3, Wh, bh, boxes, scores);
  topk_kernel<<<BATCH, 1024, 0, stream>>>(boxes, scores, nmsbuf, mcnt);
  nms_kernel<<<BATCH, 64, 0, stream>>>(nmsbuf, mcnt, out);
}

// Round 10
// 416.362 us; speedup vs baseline: 2.3842x; 1.0580x over previous
//
#include <hip/hip_runtime.h>
#include <math.h>

#define BATCH 16
#define GRID  80
#define NANCH 3
#define KTOP  300
#define NBOX  (NANCH*GRID*GRID)   // 19200
#define SORT_CAP 8192

__device__ __forceinline__ float sigmoidf_(float x){ return 1.0f/(1.0f+expf(-x)); }

// ---------------- 3x3 stride-2 conv + SiLU, v6 ----------------
// v6 = v5 + hoisted per-icl register blocks: all weight float4s (broadcast)
// and all 15 input b128s loaded up front -> one latency clump, then a pure
// independent-FMA stream (ILP hides LDS latency in-wave). launch_bounds(256,1)
// so the ~200-VGPR body cannot spill.
// Per-acc FP chain: bias; ic asc; ky asc; kx asc  == reference (bit-exact).
template<int CIN,int COUT,int C,int ICCH,int HIN,int HOUT,int TX,int TY>
__global__ __launch_bounds__(256, 1) void conv3x3s2_v6(
    const float* __restrict__ in, const float* __restrict__ w,
    const float* __restrict__ bias, float* __restrict__ out)
{
  constexpr int NTX = TX/4, NTY = TY/2, NSP = NTX*NTY, OCG = COUT/C;
  static_assert(NSP*OCG == 256, "bad thread layout");
  static_assert(C==4 || C==8, "C must be 4 or 8");
  constexpr int HR = 2*TY+1, HC = 2*TX+1;
  constexpr int NB4  = HC/4;                  // full float4 groups per row
  constexpr int PADC = ((HC+3)/4)*4 + 4;      // row stride + swizzle room
  constexpr int ILDSC = HR*PADC;
  constexpr int TBX = HOUT/TX, TBY = HOUT/TY;
  static_assert(TBX*TX == HOUT && TBY*TY == HOUT, "no masking");
  __shared__ float ilds[ICCH*ILDSC];
  __shared__ float wlds[ICCH*9*COUT];

  const int t  = threadIdx.x;
  const int sx = t % NTX;
  const int sy = (t / NTX) % NTY;
  const int og = t / NSP;                     // high bits -> wave-uniform
  int blk = blockIdx.x;
  const int bx = blk % TBX; blk /= TBX;
  const int by = blk % TBY; blk /= TBY;
  const int b  = blk;

  const int ix0 = bx*2*TX, iy0 = by*2*TY;
  const int ylim = (iy0 + HR <= HIN) ? HR : (HIN - iy0);
  const bool tail_ok = (ix0 + NB4*4 < HIN);

  float acc[C][2][4];
  #pragma unroll
  for (int j=0;j<C;++j){
    float bv = bias[og*C+j];
    #pragma unroll
    for (int py=0;py<2;++py)
      #pragma unroll
      for (int px=0;px<4;++px) acc[j][py][px]=bv;
  }

  for (int c0=0; c0<CIN; c0+=ICCH){
    __syncthreads();
    // ---- stage input halo, flat over (c, r, quad)
    for (int i=t; i<ICCH*HR*NB4; i+=256){
      int c = i/(HR*NB4), rm = i - c*(HR*NB4);
      int r = rm/NB4, m = rm - r*NB4;
      float4 v = make_float4(0.f,0.f,0.f,0.f);
      if (r < ylim)
        v = *(const float4*)(in + (size_t)(b*CIN + c0 + c)*HIN*HIN
                                + (size_t)(iy0+r)*HIN + ix0 + 4*m);
      *(float4*)(ilds + c*ILDSC + r*PADC + 4*((r>>2)&1) + 4*m) = v;
    }
    for (int i=t; i<ICCH*HR; i+=256){
      int c = i/HR, r = i - c*HR;
      float v = 0.0f;
      if (r < ylim && tail_ok)
        v = in[(size_t)(b*CIN + c0 + c)*HIN*HIN + (size_t)(iy0+r)*HIN + ix0 + NB4*4];
      ilds[c*ILDSC + r*PADC + 4*((r>>2)&1) + NB4*4] = v;
    }
    // ---- stage weights: wlds[((icl*3+ky)*3+kx)*COUT + oc]
    for (int i=t; i<ICCH*9*COUT; i+=256){
      int oc  = i % COUT;
      int k   = (i / COUT) % 9;
      int icl = i / (9*COUT);
      wlds[i] = w[((size_t)oc*CIN + c0+icl)*9 + k];
    }
    __syncthreads();

    #pragma unroll 1
    for (int icl=0; icl<ICCH; ++icl){
      // ---- hoist: all weights for this icl (broadcast reads)
      const float* wpb = wlds + icl*9*COUT + og*C;
      float4 wk0[9], wk1[9];
      #pragma unroll
      for (int k=0;k<9;++k){
        wk0[k] = *(const float4*)(wpb + k*COUT);
        if constexpr (C==8) wk1[k] = *(const float4*)(wpb + k*COUT + 4);
      }
      // ---- hoist: full 5x12 input micro-tile
      const float* ipb = ilds + icl*ILDSC + 8*sx;
      float rw[5][12];
      #pragma unroll
      for (int r=0;r<5;++r){
        const int rr = 4*sy + r;
        const float* rp = ipb + rr*PADC + 4*((rr>>2)&1);
        #pragma unroll
        for (int m=0;m<3;++m){
          float4 v4 = *(const float4*)(rp + 4*m);
          rw[r][4*m+0]=v4.x; rw[r][4*m+1]=v4.y; rw[r][4*m+2]=v4.z; rw[r][4*m+3]=v4.w;
        }
      }
      // ---- pure FMA stream (ky asc, kx asc per acc)
      #pragma unroll
      for (int py=0;py<2;++py)
        #pragma unroll
        for (int ky=0;ky<3;++ky)
          #pragma unroll
          for (int kx=0;kx<3;++kx){
            const float4 wa = wk0[ky*3+kx];
            #pragma unroll
            for (int px=0;px<4;++px){
              const float xv = rw[2*py+ky][2*px+kx];
              acc[0][py][px] += xv*wa.x; acc[1][py][px] += xv*wa.y;
              acc[2][py][px] += xv*wa.z; acc[3][py][px] += xv*wa.w;
            }
            if constexpr (C==8){
              const float4 wb = wk1[ky*3+kx];
              #pragma unroll
              for (int px=0;px<4;++px){
                const float xv = rw[2*py+ky][2*px+kx];
                acc[4][py][px] += xv*wb.x; acc[5][py][px] += xv*wb.y;
                acc[6][py][px] += xv*wb.z; acc[7][py][px] += xv*wb.w;
              }
            }
          }
    }
  }

  // ---- epilogue: SiLU + float4 stores
  const int oxb = bx*TX + sx*4;
  #pragma unroll
  for (int j=0;j<C;++j){
    int oc = og*C+j;
    #pragma unroll
    for (int py=0;py<2;++py){
      int oy = by*TY + sy*2 + py;
      float4 o4;
      float z0=acc[j][py][0], z1=acc[j][py][1], z2=acc[j][py][2], z3=acc[j][py][3];
      o4.x = z0/(1.0f+expf(-z0));
      o4.y = z1/(1.0f+expf(-z1));
      o4.z = z2/(1.0f+expf(-z2));
      o4.w = z3/(1.0f+expf(-z3));
      *(float4*)(out + ((size_t)(b*COUT+oc)*HOUT + oy)*HOUT + oxb) = o4;
    }
  }
}

// ---------------- 1x1 head (6 needed channels) + sigmoid + decode ----------------
__global__ __launch_bounds__(256) void decode_kernel(
    const float* __restrict__ f3, const float* __restrict__ Wh,
    const float* __restrict__ bh, float* __restrict__ boxes,
    float* __restrict__ scores)
{
  int idx = blockIdx.x*256 + threadIdx.x;
  const int total = BATCH*NANCH*GRID*GRID;
  if (idx >= total) return;
  int gx = idx % GRID;
  int gy = (idx/GRID)%GRID;
  int a  = (idx/(GRID*GRID))%NANCH;
  int b  = idx/(GRID*GRID*NANCH);
  const float aw[3] = {4.0f, 8.0f, 13.0f};
  const float ah[3] = {5.0f, 10.0f, 16.0f};
  const int   chs[6] = {0,1,2,3,4,15};
  const float* f = f3 + (size_t)b*64*GRID*GRID + (size_t)gy*GRID + gx;
  float acc[6];
  #pragma unroll
  for (int j=0;j<6;j++) acc[j] = bh[a*16 + chs[j]];
  for (int ic=0; ic<64; ++ic){
    float v = f[(size_t)ic*GRID*GRID];
    #pragma unroll
    for (int j=0;j<6;j++) acc[j] += v * Wh[(size_t)(a*16+chs[j])*64 + ic];
  }
  float p0 = sigmoidf_(acc[0]);
  float p1 = sigmoidf_(acc[1]);
  float p2 = sigmoidf_(acc[2]);
  float p3 = sigmoidf_(acc[3]);
  float p4 = sigmoidf_(acc[4]);
  float p15= sigmoidf_(acc[5]);
  float cx = (p0*2.0f - 0.5f + (float)gx)*8.0f;
  float cy = (p1*2.0f - 0.5f + (float)gy)*8.0f;
  float ww = p2*2.0f; ww = ww*ww*aw[a];
  float hh = p3*2.0f; hh = hh*hh*ah[a];
  float sc = p4*p15;
  sc = (sc > 0.5f) ? sc : 0.0f;
  int bi = a*GRID*GRID + gy*GRID + gx;
  float* bo = boxes + ((size_t)b*NBOX + bi)*4;
  bo[0] = cx - ww*0.5f;
  bo[1] = cy - hh*0.5f;
  bo[2] = cx + ww*0.5f;
  bo[3] = cy + hh*0.5f;
  scores[(size_t)b*NBOX + bi] = sc;
}

// ---------------- kernel A: compact + bitonic-sort top-K + gather ----------------
__global__ __launch_bounds__(1024) void topk_kernel(
    const float* __restrict__ boxes, const float* __restrict__ scores,
    float* __restrict__ nmsbuf, int* __restrict__ mcnt)
{
  __shared__ unsigned long long keys[SORT_CAP];  // 64 KB
  __shared__ int   cntM;
  __shared__ int   sel[KTOP];
  __shared__ float selsc[KTOP];
  __shared__ int   wsum[16];
  __shared__ float rs[16];
  __shared__ int   ri[16];
  __shared__ unsigned clm[(NBOX+31)/32];         // fallback claimed bitmask

  const int b = blockIdx.x;
  const int t = threadIdx.x;
  const int lane = t & 63, wv = t >> 6;
  const float* scp = scores + (size_t)b*NBOX;

  if (t == 0) cntM = 0;
  __syncthreads();

  for (int i=t; i<NBOX; i+=1024){
    float v = scp[i];
    if (v > 0.0f){
      int p = atomicAdd(&cntM, 1);
      if (p < SORT_CAP)
        keys[p] = ((unsigned long long)__float_as_uint(v) << 32)
                | (unsigned)(0xFFFFFFFFu - (unsigned)i);
    }
  }
  __syncthreads();
  const int M = cntM;
  if (t == 0) mcnt[b] = M;

  if (M <= SORT_CAP){
    int P = 64; while (P < M) P <<= 1;
    for (int i=t; i<P; i+=1024) if (i >= M) keys[i] = 0ULL;
    __syncthreads();
    for (int k=2; k<=P; k<<=1){
      for (int j=k>>1; j>0; j>>=1){
        for (int i=t; i<P; i+=1024){
          int ixj = i ^ j;
          if (ixj > i){
            unsigned long long a = keys[i], c = keys[ixj];
            bool up = ((i & k) == 0);
            if (up ? (a < c) : (a > c)){ keys[i] = c; keys[ixj] = a; }
          }
        }
        __syncthreads();
      }
    }
    const int top = (M < KTOP) ? M : KTOP;
    if (t < top){
      unsigned long long kk = keys[t];
      selsc[t] = __uint_as_float((unsigned)(kk >> 32));
      sel[t]   = (int)(0xFFFFFFFFu - (unsigned)(kk & 0xFFFFFFFFu));
    }
    if (M < KTOP){
      const int need = KTOP - M;
      const int C = (NBOX + 1023)/1024;   // 19
      int lo = t*C, hi = lo+C; if (hi > NBOX) hi = NBOX; if (lo > NBOX) lo = NBOX;
      int zc = 0;
      for (int i=lo;i<hi;i++) if (scp[i] <= 0.0f) zc++;
      int v = zc;
      #pragma unroll
      for (int off=1; off<64; off<<=1){
        int n = __shfl_up(v, off);
        if (lane >= off) v += n;
      }
      if (lane == 63) wsum[wv] = v;
      __syncthreads();
      if (t == 0){
        int a = 0;
        for (int w=0; w<16; w++){ int tmp = wsum[w]; wsum[w] = a; a += tmp; }
      }
      __syncthreads();
      int r = wsum[wv] + v - zc;
      for (int i=lo;i<hi;i++){
        if (scp[i] <= 0.0f){
          if (r < need){ sel[M+r] = i; selsc[M+r] = 0.0f; }
          r++;
        }
      }
    }
    __syncthreads();
  } else {
    for (int i=t; i<(NBOX+31)/32; i+=1024) clm[i] = 0u;
    __syncthreads();
    for (int k=0;k<KTOP;k++){
      float best = -2.0f; int bi = NBOX;
      for (int i=t;i<NBOX;i+=1024){
        if (!((clm[i>>5] >> (i&31)) & 1u)){
          float v = scp[i];
          if (v > best){ best=v; bi=i; }
        }
      }
      #pragma unroll
      for (int off=32; off>0; off>>=1){
        float ov = __shfl_down(best, off);
        int   oi = __shfl_down(bi,   off);
        if (ov > best || (ov == best && oi < bi)){ best=ov; bi=oi; }
      }
      if (lane == 0){ rs[wv]=best; ri[wv]=bi; }
      __syncthreads();
      if (t == 0){
        for (int w=1; w<16; w++)
          if (rs[w] > best || (rs[w] == best && ri[w] < bi)){ best=rs[w]; bi=ri[w]; }
        sel[k]=bi; selsc[k]=best; clm[bi>>5] |= (1u << (bi&31));
      }
      __syncthreads();
    }
  }

  if (t < KTOP){
    const float* bp = boxes + ((size_t)b*NBOX + sel[t])*4;
    float x1=bp[0], y1=bp[1], x2=bp[2], y2=bp[3];
    float* o = nmsbuf + ((size_t)b*KTOP + t)*6;
    o[0]=x1; o[1]=y1; o[2]=x2; o[3]=y2;
    o[4]=selsc[t];
    o[5]=fmaxf(x2-x1,0.0f)*fmaxf(y2-y1,0.0f);
  }
}

// ---------------- kernel B: single-wave register NMS + final write ----------------
__global__ __launch_bounds__(64, 1) void nms_kernel(
    const float* __restrict__ nmsbuf, const int* __restrict__ mcnt,
    float* __restrict__ out)
{
  const int b = blockIdx.x;
  const int lane = threadIdx.x;
  int Mtop = mcnt[b]; if (Mtop > KTOP) Mtop = KTOP;
  float X1[5],Y1[5],X2[5],Y2[5],AR[5],SC[5];
  unsigned keepm = 0;
  #pragma unroll
  for (int s5=0; s5<5; ++s5){
    int j = lane + 64*s5;
    if (j < KTOP){
      const float* p = nmsbuf + ((size_t)b*KTOP + j)*6;
      X1[s5]=p[0]; Y1[s5]=p[1]; X2[s5]=p[2]; Y2[s5]=p[3];
      SC[s5]=p[4]; AR[s5]=p[5];
      keepm |= (1u << s5);
    } else { X1[s5]=0;Y1[s5]=0;X2[s5]=0;Y2[s5]=0;AR[s5]=0;SC[s5]=0; }
  }
  for (int i=0;i<Mtop;i++){
    const int iw = i & 63, is = i >> 6;           // wave-uniform
    unsigned km = __shfl(keepm, iw);
    if ((km >> is) & 1u){
      float sx1 = (is==0)?X1[0]:(is==1)?X1[1]:(is==2)?X1[2]:(is==3)?X1[3]:X1[4];
      float sy1 = (is==0)?Y1[0]:(is==1)?Y1[1]:(is==2)?Y1[2]:(is==3)?Y1[3]:Y1[4];
      float sx2 = (is==0)?X2[0]:(is==1)?X2[1]:(is==2)?X2[2]:(is==3)?X2[3]:X2[4];
      float sy2 = (is==0)?Y2[0]:(is==1)?Y2[1]:(is==2)?Y2[2]:(is==3)?Y2[3]:Y2[4];
      float sa  = (is==0)?AR[0]:(is==1)?AR[1]:(is==2)?AR[2]:(is==3)?AR[3]:AR[4];
      float bx1=__shfl(sx1,iw), by1=__shfl(sy1,iw);
      float bx2=__shfl(sx2,iw), by2=__shfl(sy2,iw);
      float ba =__shfl(sa ,iw);
      #pragma unroll
      for (int s5=0; s5<5; ++s5){
        int j = lane + 64*s5;
        if (((keepm >> s5) & 1u) && j > i){
          float ix1=fmaxf(bx1,X1[s5]);
          float iy1=fmaxf(by1,Y1[s5]);
          float ix2=fminf(bx2,X2[s5]);
          float iy2=fminf(by2,Y2[s5]);
          float inter=fmaxf(ix2-ix1,0.0f)*fmaxf(iy2-iy1,0.0f);
          float iou = inter/(ba+AR[s5]-inter+1e-7f);
          if (iou > 0.5f) keepm &= ~(1u << s5);
        }
      }
    }
  }
  #pragma unroll
  for (int s5=0; s5<5; ++s5){
    int j = lane + 64*s5;
    if (j < KTOP){
      float scv = SC[s5];
      float kf  = (((keepm >> s5) & 1u) && scv > 0.0f) ? 1.0f : 0.0f;
      float* o = out + ((size_t)b*KTOP + j)*6;
      o[0]=X1[s5]; o[1]=Y1[s5]; o[2]=X2[s5]; o[3]=Y2[s5];
      o[4]=scv; o[5]=kf;
    }
  }
}

extern "C" void kernel_launch(void* const* d_in, const int* in_sizes, int n_in,
                              void* d_out, int out_size, void* d_ws, size_t ws_size,
                              hipStream_t stream) {
  const float* x  = (const float*)d_in[0];
  const float* W1 = (const float*)d_in[1];
  const float* b1 = (const float*)d_in[2];
  const float* W2 = (const float*)d_in[3];
  const float* b2 = (const float*)d_in[4];
  const float* W3 = (const float*)d_in[5];
  const float* b3 = (const float*)d_in[6];
  const float* Wh = (const float*)d_in[7];
  const float* bh = (const float*)d_in[8];
  float* out = (float*)d_out;
  float* ws  = (float*)d_ws;

  float* f1     = ws;               // 16x16x320x320 = 26,214,400
  float* f2     = ws + 26214400;    // 16x32x160x160 = 13,107,200
  float* f3     = ws;               // reuse f1: 16x64x80x80
  float* boxes  = ws + 26214400;    // reuse f2: 16x19200x4
  float* scores = boxes + 1228800;  // 16x19200
  float* nmsbuf = scores + 307200;  // 16x300x6 = 28,800
  int*   mcnt   = (int*)(nmsbuf + 28800);

  // conv1: 3->16, tile 64x16, C=8 (OCG=2), ICCH=1 -> 1600 blocks
  conv3x3s2_v6<3,16,8,1,640,320,64,16><<<5*20*BATCH, 256, 0, stream>>>(x,  W1, b1, f1);
  // conv2: 16->32, tile 32x16, C=8 (OCG=4), ICCH=2 -> 800 blocks
  conv3x3s2_v6<16,32,8,2,320,160,32,16><<<5*10*BATCH, 256, 0, stream>>>(f1, W2, b2, f2);
  // conv3: 32->64, tile 16x8, C=4 (OCG=16), ICCH=4 -> 800 blocks
  conv3x3s2_v6<32,64,4,4,160,80,16,8><<<5*10*BATCH, 256, 0, stream>>>(f2, W3, b3, f3);

  decode_kernel<<<(BATCH*NANCH*GRID*GRID+255)/256, 256, 0, stream>>>(f3, Wh, bh, boxes, scores);
  topk_kernel<<<BATCH, 1024, 0, stream>>>(boxes, scores, nmsbuf, mcnt);
  nms_kernel<<<BATCH, 64, 0, stream>>>(nmsbuf, mcnt, out);
}

// Round 11
// 403.658 us; speedup vs baseline: 2.4592x; 1.0315x over previous
//
#include <hip/hip_runtime.h>
#include <math.h>

#define BATCH 16
#define GRID  80
#define NANCH 3
#define KTOP  300
#define NBOX  (NANCH*GRID*GRID)   // 19200
#define SORT_CAP 8192

__device__ __forceinline__ float sigmoidf_(float x){ return 1.0f/(1.0f+expf(-x)); }

// ---------------- 3x3 stride-2 conv + SiLU, v7 ----------------
// v7 = v6 + register double-buffering of the global->LDS staging:
// chunk c+1 global loads issue into registers BEFORE chunk c's FMA stream,
// regs spill to the alternate LDS buffer after compute, ONE barrier/chunk.
// Global-load latency is hidden behind ~2300 cyc of FMAs in-wave (grid gives
// only ~3 blocks/CU, so cross-block TLP can't do it for us).
// Per-acc FP chain: bias; ic asc; ky asc; kx asc == reference (bit-exact).
template<int CIN,int COUT,int C,int ICCH,int HIN,int HOUT,int TX,int TY>
__global__ __launch_bounds__(256, 1) void conv3x3s2_v7(
    const float* __restrict__ in, const float* __restrict__ w,
    const float* __restrict__ bias, float* __restrict__ out)
{
  constexpr int NTX = TX/4, NTY = TY/2, NSP = NTX*NTY, OCG = COUT/C;
  static_assert(NSP*OCG == 256, "bad thread layout");
  static_assert(C==4 || C==8, "C must be 4 or 8");
  constexpr int HR = 2*TY+1, HC = 2*TX+1;
  constexpr int NB4  = HC/4;                  // full float4 groups per row
  constexpr int PADC = ((HC+3)/4)*4 + 4;      // row stride + swizzle room
  constexpr int ILDSC = HR*PADC;
  constexpr int TBX = HOUT/TX, TBY = HOUT/TY;
  static_assert(TBX*TX == HOUT && TBY*TY == HOUT, "no masking");
  constexpr int NCH  = CIN/ICCH;
  constexpr int NH4  = ICCH*HR*NB4;           // float4 halo elements
  constexpr int NH1  = ICCH*HR;               // tail column elements
  constexpr int NWT  = ICCH*9*COUT;           // weight floats per chunk
  constexpr int NLD4 = (NH4+255)/256;
  constexpr int NLD1 = (NH1+255)/256;
  constexpr int NLDW = (NWT+255)/256;
  __shared__ float ilds[2][ICCH*ILDSC];
  __shared__ float wlds[2][NWT];

  const int t  = threadIdx.x;
  const int sx = t % NTX;
  const int sy = (t / NTX) % NTY;
  const int og = t / NSP;                     // high bits -> wave-uniform
  int blk = blockIdx.x;
  const int bx = blk % TBX; blk /= TBX;
  const int by = blk % TBY; blk /= TBY;
  const int b  = blk;

  const int ix0 = bx*2*TX, iy0 = by*2*TY;
  const int ylim = (iy0 + HR <= HIN) ? HR : (HIN - iy0);
  const bool tail_ok = (ix0 + NB4*4 < HIN);

  float4 hreg[NLD4];
  float  treg[NLD1];
  float  wreg[NLDW];

  auto load_regs = [&](int c0){
    #pragma unroll
    for (int l=0;l<NLD4;++l){
      int i = t + 256*l;
      float4 v = make_float4(0.f,0.f,0.f,0.f);
      if (i < NH4){
        int c = i/(HR*NB4), rm = i - c*(HR*NB4);
        int r = rm/NB4, m = rm - r*NB4;
        if (r < ylim)
          v = *(const float4*)(in + (size_t)(b*CIN + c0 + c)*HIN*HIN
                                  + (size_t)(iy0+r)*HIN + ix0 + 4*m);
      }
      hreg[l] = v;
    }
    #pragma unroll
    for (int l=0;l<NLD1;++l){
      int i = t + 256*l;
      float v = 0.f;
      if (i < NH1){
        int c = i/HR, r = i - c*HR;
        if (r < ylim && tail_ok)
          v = in[(size_t)(b*CIN + c0 + c)*HIN*HIN + (size_t)(iy0+r)*HIN + ix0 + NB4*4];
      }
      treg[l] = v;
    }
    #pragma unroll
    for (int l=0;l<NLDW;++l){
      int i = t + 256*l;
      float v = 0.f;
      if (i < NWT){
        int oc  = i % COUT;
        int k   = (i / COUT) % 9;
        int icl = i / (9*COUT);
        v = w[((size_t)oc*CIN + c0+icl)*9 + k];
      }
      wreg[l] = v;
    }
  };

  auto write_lds = [&](int bufi){
    #pragma unroll
    for (int l=0;l<NLD4;++l){
      int i = t + 256*l;
      if (i < NH4){
        int c = i/(HR*NB4), rm = i - c*(HR*NB4);
        int r = rm/NB4, m = rm - r*NB4;
        *(float4*)(&ilds[bufi][c*ILDSC + r*PADC + 4*((r>>2)&1) + 4*m]) = hreg[l];
      }
    }
    #pragma unroll
    for (int l=0;l<NLD1;++l){
      int i = t + 256*l;
      if (i < NH1){
        int c = i/HR, r = i - c*HR;
        ilds[bufi][c*ILDSC + r*PADC + 4*((r>>2)&1) + NB4*4] = treg[l];
      }
    }
    #pragma unroll
    for (int l=0;l<NLDW;++l){
      int i = t + 256*l;
      if (i < NWT) wlds[bufi][i] = wreg[l];
    }
  };

  float acc[C][2][4];
  #pragma unroll
  for (int j=0;j<C;++j){
    float bv = bias[og*C+j];
    #pragma unroll
    for (int py=0;py<2;++py)
      #pragma unroll
      for (int px=0;px<4;++px) acc[j][py][px]=bv;
  }

  load_regs(0);
  write_lds(0);
  __syncthreads();

  #pragma unroll 1
  for (int ch=0; ch<NCH; ++ch){
    const int cur = ch & 1;
    if (ch+1 < NCH) load_regs((ch+1)*ICCH);   // in-flight during compute

    #pragma unroll 1
    for (int icl=0; icl<ICCH; ++icl){
      // hoist: weights (broadcast) + full 5x12 input micro-tile
      const float* wpb = &wlds[cur][icl*9*COUT] + og*C;
      float4 wk0[9], wk1[9];
      #pragma unroll
      for (int k=0;k<9;++k){
        wk0[k] = *(const float4*)(wpb + k*COUT);
        if constexpr (C==8) wk1[k] = *(const float4*)(wpb + k*COUT + 4);
      }
      const float* ipb = &ilds[cur][icl*ILDSC] + 8*sx;
      float rw[5][12];
      #pragma unroll
      for (int r=0;r<5;++r){
        const int rr = 4*sy + r;
        const float* rp = ipb + rr*PADC + 4*((rr>>2)&1);
        #pragma unroll
        for (int m=0;m<3;++m){
          float4 v4 = *(const float4*)(rp + 4*m);
          rw[r][4*m+0]=v4.x; rw[r][4*m+1]=v4.y; rw[r][4*m+2]=v4.z; rw[r][4*m+3]=v4.w;
        }
      }
      #pragma unroll
      for (int py=0;py<2;++py)
        #pragma unroll
        for (int ky=0;ky<3;++ky)
          #pragma unroll
          for (int kx=0;kx<3;++kx){
            const float4 wa = wk0[ky*3+kx];
            #pragma unroll
            for (int px=0;px<4;++px){
              const float xv = rw[2*py+ky][2*px+kx];
              acc[0][py][px] += xv*wa.x; acc[1][py][px] += xv*wa.y;
              acc[2][py][px] += xv*wa.z; acc[3][py][px] += xv*wa.w;
            }
            if constexpr (C==8){
              const float4 wb = wk1[ky*3+kx];
              #pragma unroll
              for (int px=0;px<4;++px){
                const float xv = rw[2*py+ky][2*px+kx];
                acc[4][py][px] += xv*wb.x; acc[5][py][px] += xv*wb.y;
                acc[6][py][px] += xv*wb.z; acc[7][py][px] += xv*wb.w;
              }
            }
          }
    }

    if (ch+1 < NCH) write_lds((ch+1)&1);      // waits vmcnt here (free)
    __syncthreads();
  }

  // ---- epilogue: SiLU + float4 stores
  const int oxb = bx*TX + sx*4;
  #pragma unroll
  for (int j=0;j<C;++j){
    int oc = og*C+j;
    #pragma unroll
    for (int py=0;py<2;++py){
      int oy = by*TY + sy*2 + py;
      float4 o4;
      float z0=acc[j][py][0], z1=acc[j][py][1], z2=acc[j][py][2], z3=acc[j][py][3];
      o4.x = z0/(1.0f+expf(-z0));
      o4.y = z1/(1.0f+expf(-z1));
      o4.z = z2/(1.0f+expf(-z2));
      o4.w = z3/(1.0f+expf(-z3));
      *(float4*)(out + ((size_t)(b*COUT+oc)*HOUT + oy)*HOUT + oxb) = o4;
    }
  }
}

// ---------------- 1x1 head (6 needed channels) + sigmoid + decode ----------------
__global__ __launch_bounds__(256) void decode_kernel(
    const float* __restrict__ f3, const float* __restrict__ Wh,
    const float* __restrict__ bh, float* __restrict__ boxes,
    float* __restrict__ scores)
{
  int idx = blockIdx.x*256 + threadIdx.x;
  const int total = BATCH*NANCH*GRID*GRID;
  if (idx >= total) return;
  int gx = idx % GRID;
  int gy = (idx/GRID)%GRID;
  int a  = (idx/(GRID*GRID))%NANCH;
  int b  = idx/(GRID*GRID*NANCH);
  const float aw[3] = {4.0f, 8.0f, 13.0f};
  const float ah[3] = {5.0f, 10.0f, 16.0f};
  const int   chs[6] = {0,1,2,3,4,15};
  const float* f = f3 + (size_t)b*64*GRID*GRID + (size_t)gy*GRID + gx;
  float acc[6];
  #pragma unroll
  for (int j=0;j<6;j++) acc[j] = bh[a*16 + chs[j]];
  for (int ic=0; ic<64; ++ic){
    float v = f[(size_t)ic*GRID*GRID];
    #pragma unroll
    for (int j=0;j<6;j++) acc[j] += v * Wh[(size_t)(a*16+chs[j])*64 + ic];
  }
  float p0 = sigmoidf_(acc[0]);
  float p1 = sigmoidf_(acc[1]);
  float p2 = sigmoidf_(acc[2]);
  float p3 = sigmoidf_(acc[3]);
  float p4 = sigmoidf_(acc[4]);
  float p15= sigmoidf_(acc[5]);
  float cx = (p0*2.0f - 0.5f + (float)gx)*8.0f;
  float cy = (p1*2.0f - 0.5f + (float)gy)*8.0f;
  float ww = p2*2.0f; ww = ww*ww*aw[a];
  float hh = p3*2.0f; hh = hh*hh*ah[a];
  float sc = p4*p15;
  sc = (sc > 0.5f) ? sc : 0.0f;
  int bi = a*GRID*GRID + gy*GRID + gx;
  float* bo = boxes + ((size_t)b*NBOX + bi)*4;
  bo[0] = cx - ww*0.5f;
  bo[1] = cy - hh*0.5f;
  bo[2] = cx + ww*0.5f;
  bo[3] = cy + hh*0.5f;
  scores[(size_t)b*NBOX + bi] = sc;
}

// ---------------- kernel A: compact + bitonic-sort top-K + gather ----------------
__global__ __launch_bounds__(1024) void topk_kernel(
    const float* __restrict__ boxes, const float* __restrict__ scores,
    float* __restrict__ nmsbuf, int* __restrict__ mcnt)
{
  __shared__ unsigned long long keys[SORT_CAP];  // 64 KB
  __shared__ int   cntM;
  __shared__ int   sel[KTOP];
  __shared__ float selsc[KTOP];
  __shared__ int   wsum[16];
  __shared__ float rs[16];
  __shared__ int   ri[16];
  __shared__ unsigned clm[(NBOX+31)/32];         // fallback claimed bitmask

  const int b = blockIdx.x;
  const int t = threadIdx.x;
  const int lane = t & 63, wv = t >> 6;
  const float* scp = scores + (size_t)b*NBOX;

  if (t == 0) cntM = 0;
  __syncthreads();

  for (int i=t; i<NBOX; i+=1024){
    float v = scp[i];
    if (v > 0.0f){
      int p = atomicAdd(&cntM, 1);
      if (p < SORT_CAP)
        keys[p] = ((unsigned long long)__float_as_uint(v) << 32)
                | (unsigned)(0xFFFFFFFFu - (unsigned)i);
    }
  }
  __syncthreads();
  const int M = cntM;
  if (t == 0) mcnt[b] = M;

  if (M <= SORT_CAP){
    int P = 64; while (P < M) P <<= 1;
    for (int i=t; i<P; i+=1024) if (i >= M) keys[i] = 0ULL;
    __syncthreads();
    for (int k=2; k<=P; k<<=1){
      for (int j=k>>1; j>0; j>>=1){
        for (int i=t; i<P; i+=1024){
          int ixj = i ^ j;
          if (ixj > i){
            unsigned long long a = keys[i], c = keys[ixj];
            bool up = ((i & k) == 0);
            if (up ? (a < c) : (a > c)){ keys[i] = c; keys[ixj] = a; }
          }
        }
        __syncthreads();
      }
    }
    const int top = (M < KTOP) ? M : KTOP;
    if (t < top){
      unsigned long long kk = keys[t];
      selsc[t] = __uint_as_float((unsigned)(kk >> 32));
      sel[t]   = (int)(0xFFFFFFFFu - (unsigned)(kk & 0xFFFFFFFFu));
    }
    if (M < KTOP){
      const int need = KTOP - M;
      const int C = (NBOX + 1023)/1024;   // 19
      int lo = t*C, hi = lo+C; if (hi > NBOX) hi = NBOX; if (lo > NBOX) lo = NBOX;
      int zc = 0;
      for (int i=lo;i<hi;i++) if (scp[i] <= 0.0f) zc++;
      int v = zc;
      #pragma unroll
      for (int off=1; off<64; off<<=1){
        int n = __shfl_up(v, off);
        if (lane >= off) v += n;
      }
      if (lane == 63) wsum[wv] = v;
      __syncthreads();
      if (t == 0){
        int a = 0;
        for (int w=0; w<16; w++){ int tmp = wsum[w]; wsum[w] = a; a += tmp; }
      }
      __syncthreads();
      int r = wsum[wv] + v - zc;
      for (int i=lo;i<hi;i++){
        if (scp[i] <= 0.0f){
          if (r < need){ sel[M+r] = i; selsc[M+r] = 0.0f; }
          r++;
        }
      }
    }
    __syncthreads();
  } else {
    for (int i=t; i<(NBOX+31)/32; i+=1024) clm[i] = 0u;
    __syncthreads();
    for (int k=0;k<KTOP;k++){
      float best = -2.0f; int bi = NBOX;
      for (int i=t;i<NBOX;i+=1024){
        if (!((clm[i>>5] >> (i&31)) & 1u)){
          float v = scp[i];
          if (v > best){ best=v; bi=i; }
        }
      }
      #pragma unroll
      for (int off=32; off>0; off>>=1){
        float ov = __shfl_down(best, off);
        int   oi = __shfl_down(bi,   off);
        if (ov > best || (ov == best && oi < bi)){ best=ov; bi=oi; }
      }
      if (lane == 0){ rs[wv]=best; ri[wv]=bi; }
      __syncthreads();
      if (t == 0){
        for (int w=1; w<16; w++)
          if (rs[w] > best || (rs[w] == best && ri[w] < bi)){ best=rs[w]; bi=ri[w]; }
        sel[k]=bi; selsc[k]=best; clm[bi>>5] |= (1u << (bi&31));
      }
      __syncthreads();
    }
  }

  if (t < KTOP){
    const float* bp = boxes + ((size_t)b*NBOX + sel[t])*4;
    float x1=bp[0], y1=bp[1], x2=bp[2], y2=bp[3];
    float* o = nmsbuf + ((size_t)b*KTOP + t)*6;
    o[0]=x1; o[1]=y1; o[2]=x2; o[3]=y2;
    o[4]=selsc[t];
    o[5]=fmaxf(x2-x1,0.0f)*fmaxf(y2-y1,0.0f);
  }
}

// ---------------- kernel B: single-wave register NMS + final write ----------------
__global__ __launch_bounds__(64, 1) void nms_kernel(
    const float* __restrict__ nmsbuf, const int* __restrict__ mcnt,
    float* __restrict__ out)
{
  const int b = blockIdx.x;
  const int lane = threadIdx.x;
  int Mtop = mcnt[b]; if (Mtop > KTOP) Mtop = KTOP;
  float X1[5],Y1[5],X2[5],Y2[5],AR[5],SC[5];
  unsigned keepm = 0;
  #pragma unroll
  for (int s5=0; s5<5; ++s5){
    int j = lane + 64*s5;
    if (j < KTOP){
      const float* p = nmsbuf + ((size_t)b*KTOP + j)*6;
      X1[s5]=p[0]; Y1[s5]=p[1]; X2[s5]=p[2]; Y2[s5]=p[3];
      SC[s5]=p[4]; AR[s5]=p[5];
      keepm |= (1u << s5);
    } else { X1[s5]=0;Y1[s5]=0;X2[s5]=0;Y2[s5]=0;AR[s5]=0;SC[s5]=0; }
  }
  for (int i=0;i<Mtop;i++){
    const int iw = i & 63, is = i >> 6;           // wave-uniform
    unsigned km = __shfl(keepm, iw);
    if ((km >> is) & 1u){
      float sx1 = (is==0)?X1[0]:(is==1)?X1[1]:(is==2)?X1[2]:(is==3)?X1[3]:X1[4];
      float sy1 = (is==0)?Y1[0]:(is==1)?Y1[1]:(is==2)?Y1[2]:(is==3)?Y1[3]:Y1[4];
      float sx2 = (is==0)?X2[0]:(is==1)?X2[1]:(is==2)?X2[2]:(is==3)?X2[3]:X2[4];
      float sy2 = (is==0)?Y2[0]:(is==1)?Y2[1]:(is==2)?Y2[2]:(is==3)?Y2[3]:Y2[4];
      float sa  = (is==0)?AR[0]:(is==1)?AR[1]:(is==2)?AR[2]:(is==3)?AR[3]:AR[4];
      float bx1=__shfl(sx1,iw), by1=__shfl(sy1,iw);
      float bx2=__shfl(sx2,iw), by2=__shfl(sy2,iw);
      float ba =__shfl(sa ,iw);
      #pragma unroll
      for (int s5=0; s5<5; ++s5){
        int j = lane + 64*s5;
        if (((keepm >> s5) & 1u) && j > i){
          float ix1=fmaxf(bx1,X1[s5]);
          float iy1=fmaxf(by1,Y1[s5]);
          float ix2=fminf(bx2,X2[s5]);
          float iy2=fminf(by2,Y2[s5]);
          float inter=fmaxf(ix2-ix1,0.0f)*fmaxf(iy2-iy1,0.0f);
          float iou = inter/(ba+AR[s5]-inter+1e-7f);
          if (iou > 0.5f) keepm &= ~(1u << s5);
        }
      }
    }
  }
  #pragma unroll
  for (int s5=0; s5<5; ++s5){
    int j = lane + 64*s5;
    if (j < KTOP){
      float scv = SC[s5];
      float kf  = (((keepm >> s5) & 1u) && scv > 0.0f) ? 1.0f : 0.0f;
      float* o = out + ((size_t)b*KTOP + j)*6;
      o[0]=X1[s5]; o[1]=Y1[s5]; o[2]=X2[s5]; o[3]=Y2[s5];
      o[4]=scv; o[5]=kf;
    }
  }
}

extern "C" void kernel_launch(void* const* d_in, const int* in_sizes, int n_in,
                              void* d_out, int out_size, void* d_ws, size_t ws_size,
                              hipStream_t stream) {
  const float* x  = (const float*)d_in[0];
  const float* W1 = (const float*)d_in[1];
  const float* b1 = (const float*)d_in[2];
  const float* W2 = (const float*)d_in[3];
  const float* b2 = (const float*)d_in[4];
  const float* W3 = (const float*)d_in[5];
  const float* b3 = (const float*)d_in[6];
  const float* Wh = (const float*)d_in[7];
  const float* bh = (const float*)d_in[8];
  float* out = (float*)d_out;
  float* ws  = (float*)d_ws;

  float* f1     = ws;               // 16x16x320x320 = 26,214,400
  float* f2     = ws + 26214400;    // 16x32x160x160 = 13,107,200
  float* f3     = ws;               // reuse f1: 16x64x80x80
  float* boxes  = ws + 26214400;    // reuse f2: 16x19200x4
  float* scores = boxes + 1228800;  // 16x19200
  float* nmsbuf = scores + 307200;  // 16x300x6 = 28,800
  int*   mcnt   = (int*)(nmsbuf + 28800);

  // conv1: 3->16, tile 64x16, C=8 (OCG=2), ICCH=1 -> 1600 blocks
  conv3x3s2_v7<3,16,8,1,640,320,64,16><<<5*20*BATCH, 256, 0, stream>>>(x,  W1, b1, f1);
  // conv2: 16->32, tile 32x16, C=8 (OCG=4), ICCH=2 -> 800 blocks
  conv3x3s2_v7<16,32,8,2,320,160,32,16><<<5*10*BATCH, 256, 0, stream>>>(f1, W2, b2, f2);
  // conv3: 32->64, tile 16x8, C=4 (OCG=16), ICCH=4 -> 800 blocks
  conv3x3s2_v7<32,64,4,4,160,80,16,8><<<5*10*BATCH, 256, 0, stream>>>(f2, W3, b3, f3);

  decode_kernel<<<(BATCH*NANCH*GRID*GRID+255)/256, 256, 0, stream>>>(f3, Wh, bh, boxes, scores);
  topk_kernel<<<BATCH, 1024, 0, stream>>>(boxes, scores, nmsbuf, mcnt);
  nms_kernel<<<BATCH, 64, 0, stream>>>(nmsbuf, mcnt, out);
}

// Round 12
// 386.869 us; speedup vs baseline: 2.5659x; 1.0434x over previous
//
#include <hip/hip_runtime.h>
#include <math.h>

#define BATCH 16
#define GRID  80
#define NANCH 3
#define KTOP  300
#define NBOX  (NANCH*GRID*GRID)   // 19200
#define SORT_CAP 8192

__device__ __forceinline__ float sigmoidf_(float x){ return 1.0f/(1.0f+expf(-x)); }

// ---------------- 3x3 stride-2 conv + SiLU, v7 (MINW = min waves/EU) ----------------
template<int CIN,int COUT,int C,int ICCH,int HIN,int HOUT,int TX,int TY,int MINW>
__global__ __launch_bounds__(256, MINW) void conv3x3s2_v7(
    const float* __restrict__ in, const float* __restrict__ w,
    const float* __restrict__ bias, float* __restrict__ out)
{
  constexpr int NTX = TX/4, NTY = TY/2, NSP = NTX*NTY, OCG = COUT/C;
  static_assert(NSP*OCG == 256, "bad thread layout");
  static_assert(C==4 || C==8, "C must be 4 or 8");
  constexpr int HR = 2*TY+1, HC = 2*TX+1;
  constexpr int NB4  = HC/4;
  constexpr int PADC = ((HC+3)/4)*4 + 4;
  constexpr int ILDSC = HR*PADC;
  constexpr int TBX = HOUT/TX, TBY = HOUT/TY;
  static_assert(TBX*TX == HOUT && TBY*TY == HOUT, "no masking");
  constexpr int NCH  = CIN/ICCH;
  constexpr int NH4  = ICCH*HR*NB4;
  constexpr int NH1  = ICCH*HR;
  constexpr int NWT  = ICCH*9*COUT;
  constexpr int NLD4 = (NH4+255)/256;
  constexpr int NLD1 = (NH1+255)/256;
  constexpr int NLDW = (NWT+255)/256;
  __shared__ float ilds[2][ICCH*ILDSC];
  __shared__ float wlds[2][NWT];

  const int t  = threadIdx.x;
  const int sx = t % NTX;
  const int sy = (t / NTX) % NTY;
  const int og = t / NSP;
  int blk = blockIdx.x;
  const int bx = blk % TBX; blk /= TBX;
  const int by = blk % TBY; blk /= TBY;
  const int b  = blk;

  const int ix0 = bx*2*TX, iy0 = by*2*TY;
  const int ylim = (iy0 + HR <= HIN) ? HR : (HIN - iy0);
  const bool tail_ok = (ix0 + NB4*4 < HIN);

  float4 hreg[NLD4];
  float  treg[NLD1];
  float  wreg[NLDW];

  auto load_regs = [&](int c0){
    #pragma unroll
    for (int l=0;l<NLD4;++l){
      int i = t + 256*l;
      float4 v = make_float4(0.f,0.f,0.f,0.f);
      if (i < NH4){
        int c = i/(HR*NB4), rm = i - c*(HR*NB4);
        int r = rm/NB4, m = rm - r*NB4;
        if (r < ylim)
          v = *(const float4*)(in + (size_t)(b*CIN + c0 + c)*HIN*HIN
                                  + (size_t)(iy0+r)*HIN + ix0 + 4*m);
      }
      hreg[l] = v;
    }
    #pragma unroll
    for (int l=0;l<NLD1;++l){
      int i = t + 256*l;
      float v = 0.f;
      if (i < NH1){
        int c = i/HR, r = i - c*HR;
        if (r < ylim && tail_ok)
          v = in[(size_t)(b*CIN + c0 + c)*HIN*HIN + (size_t)(iy0+r)*HIN + ix0 + NB4*4];
      }
      treg[l] = v;
    }
    #pragma unroll
    for (int l=0;l<NLDW;++l){
      int i = t + 256*l;
      float v = 0.f;
      if (i < NWT){
        int oc  = i % COUT;
        int k   = (i / COUT) % 9;
        int icl = i / (9*COUT);
        v = w[((size_t)oc*CIN + c0+icl)*9 + k];
      }
      wreg[l] = v;
    }
  };

  auto write_lds = [&](int bufi){
    #pragma unroll
    for (int l=0;l<NLD4;++l){
      int i = t + 256*l;
      if (i < NH4){
        int c = i/(HR*NB4), rm = i - c*(HR*NB4);
        int r = rm/NB4, m = rm - r*NB4;
        *(float4*)(&ilds[bufi][c*ILDSC + r*PADC + 4*((r>>2)&1) + 4*m]) = hreg[l];
      }
    }
    #pragma unroll
    for (int l=0;l<NLD1;++l){
      int i = t + 256*l;
      if (i < NH1){
        int c = i/HR, r = i - c*HR;
        ilds[bufi][c*ILDSC + r*PADC + 4*((r>>2)&1) + NB4*4] = treg[l];
      }
    }
    #pragma unroll
    for (int l=0;l<NLDW;++l){
      int i = t + 256*l;
      if (i < NWT) wlds[bufi][i] = wreg[l];
    }
  };

  float acc[C][2][4];
  #pragma unroll
  for (int j=0;j<C;++j){
    float bv = bias[og*C+j];
    #pragma unroll
    for (int py=0;py<2;++py)
      #pragma unroll
      for (int px=0;px<4;++px) acc[j][py][px]=bv;
  }

  load_regs(0);
  write_lds(0);
  __syncthreads();

  #pragma unroll 1
  for (int ch=0; ch<NCH; ++ch){
    const int cur = ch & 1;
    if (ch+1 < NCH) load_regs((ch+1)*ICCH);

    #pragma unroll 1
    for (int icl=0; icl<ICCH; ++icl){
      const float* wpb = &wlds[cur][icl*9*COUT] + og*C;
      float4 wk0[9], wk1[9];
      #pragma unroll
      for (int k=0;k<9;++k){
        wk0[k] = *(const float4*)(wpb + k*COUT);
        if constexpr (C==8) wk1[k] = *(const float4*)(wpb + k*COUT + 4);
      }
      const float* ipb = &ilds[cur][icl*ILDSC] + 8*sx;
      float rw[5][12];
      #pragma unroll
      for (int r=0;r<5;++r){
        const int rr = 4*sy + r;
        const float* rp = ipb + rr*PADC + 4*((rr>>2)&1);
        #pragma unroll
        for (int m=0;m<3;++m){
          float4 v4 = *(const float4*)(rp + 4*m);
          rw[r][4*m+0]=v4.x; rw[r][4*m+1]=v4.y; rw[r][4*m+2]=v4.z; rw[r][4*m+3]=v4.w;
        }
      }
      #pragma unroll
      for (int py=0;py<2;++py)
        #pragma unroll
        for (int ky=0;ky<3;++ky)
          #pragma unroll
          for (int kx=0;kx<3;++kx){
            const float4 wa = wk0[ky*3+kx];
            #pragma unroll
            for (int px=0;px<4;++px){
              const float xv = rw[2*py+ky][2*px+kx];
              acc[0][py][px] += xv*wa.x; acc[1][py][px] += xv*wa.y;
              acc[2][py][px] += xv*wa.z; acc[3][py][px] += xv*wa.w;
            }
            if constexpr (C==8){
              const float4 wb = wk1[ky*3+kx];
              #pragma unroll
              for (int px=0;px<4;++px){
                const float xv = rw[2*py+ky][2*px+kx];
                acc[4][py][px] += xv*wb.x; acc[5][py][px] += xv*wb.y;
                acc[6][py][px] += xv*wb.z; acc[7][py][px] += xv*wb.w;
              }
            }
          }
    }

    if (ch+1 < NCH) write_lds((ch+1)&1);
    __syncthreads();
  }

  const int oxb = bx*TX + sx*4;
  #pragma unroll
  for (int j=0;j<C;++j){
    int oc = og*C+j;
    #pragma unroll
    for (int py=0;py<2;++py){
      int oy = by*TY + sy*2 + py;
      float4 o4;
      float z0=acc[j][py][0], z1=acc[j][py][1], z2=acc[j][py][2], z3=acc[j][py][3];
      o4.x = z0/(1.0f+expf(-z0));
      o4.y = z1/(1.0f+expf(-z1));
      o4.z = z2/(1.0f+expf(-z2));
      o4.w = z3/(1.0f+expf(-z3));
      *(float4*)(out + ((size_t)(b*COUT+oc)*HOUT + oy)*HOUT + oxb) = o4;
    }
  }
}

// ---------------- conv3 + head + decode, fused (f3 never leaves the CU) ----------------
// conv3 body = v7 instance <32,64,4,4,160,80,16,8>; epilogue writes SiLU tile
// to LDS (stride 68 breaks 64-stride bank alias), then 384 head dot-products
// (K=64, 6 channels, LDS weights) + decode + boxes/scores writes.
// Head FP chain identical to old decode_kernel (bias-first, ic ascending).
__global__ __launch_bounds__(256, 1) void conv3_decode_fused(
    const float* __restrict__ in,   // f2
    const float* __restrict__ w,    // W3
    const float* __restrict__ bias, // b3
    const float* __restrict__ wh,   // Wh [48][64]
    const float* __restrict__ bh,   // bh [48]
    float* __restrict__ boxes, float* __restrict__ scores)
{
  constexpr int CIN=32, COUT=64, C=4, ICCH=4, HIN=160, TX=16, TY=8;
  constexpr int NTX=TX/4, NTY=TY/2, NSP=NTX*NTY;      // 4,4,16
  constexpr int HR=2*TY+1, HC=2*TX+1;                 // 17,33
  constexpr int NB4=HC/4;                             // 8
  constexpr int PADC=((HC+3)/4)*4+4;                  // 40
  constexpr int ILDSC=HR*PADC;                        // 680
  constexpr int TBX=5, TBY=10;
  constexpr int NCH=CIN/ICCH;                         // 8
  constexpr int NH4=ICCH*HR*NB4;                      // 544
  constexpr int NH1=ICCH*HR;                          // 68
  constexpr int NWT=ICCH*9*COUT;                      // 2304
  constexpr int NLD4=(NH4+255)/256, NLD1=(NH1+255)/256, NLDW=(NWT+255)/256;
  __shared__ float smem[11232];
  float* ildsb = smem;              // [2][ICCH*ILDSC] = 5440
  float* wldsb = smem + 5440;       // [2][NWT] = 4608
  float* f3l   = smem;              // [128][68] aliased (post-conv)
  float* whl   = smem + 10048;      // [18][64]
  float* bhl   = smem + 11200;      // [18]

  const int t  = threadIdx.x;
  const int sx = t % NTX;
  const int sy = (t / NTX) % NTY;
  const int og = t / NSP;
  int blk = blockIdx.x;
  const int bx = blk % TBX; blk /= TBX;
  const int by = blk % TBY; blk /= TBY;
  const int b  = blk;

  // stage head weights once (region doesn't alias conv buffers)
  {
    const int chs[6] = {0,1,2,3,4,15};
    for (int i=t; i<1152; i+=256){
      int row = i >> 6, ic = i & 63;
      int a = row/6, j = row - 6*a;
      whl[i] = wh[(size_t)(a*16+chs[j])*64 + ic];
    }
    if (t < 18){ int a=t/6, j=t-6*a; bhl[t] = bh[a*16+chs[j]]; }
  }

  const int ix0 = bx*2*TX, iy0 = by*2*TY;
  const int ylim = (iy0 + HR <= HIN) ? HR : (HIN - iy0);
  const bool tail_ok = (ix0 + NB4*4 < HIN);

  float4 hreg[NLD4];
  float  treg[NLD1];
  float  wreg[NLDW];

  auto load_regs = [&](int c0){
    #pragma unroll
    for (int l=0;l<NLD4;++l){
      int i = t + 256*l;
      float4 v = make_float4(0.f,0.f,0.f,0.f);
      if (i < NH4){
        int c = i/(HR*NB4), rm = i - c*(HR*NB4);
        int r = rm/NB4, m = rm - r*NB4;
        if (r < ylim)
          v = *(const float4*)(in + (size_t)(b*CIN + c0 + c)*HIN*HIN
                                  + (size_t)(iy0+r)*HIN + ix0 + 4*m);
      }
      hreg[l] = v;
    }
    #pragma unroll
    for (int l=0;l<NLD1;++l){
      int i = t + 256*l;
      float v = 0.f;
      if (i < NH1){
        int c = i/HR, r = i - c*HR;
        if (r < ylim && tail_ok)
          v = in[(size_t)(b*CIN + c0 + c)*HIN*HIN + (size_t)(iy0+r)*HIN + ix0 + NB4*4];
      }
      treg[l] = v;
    }
    #pragma unroll
    for (int l=0;l<NLDW;++l){
      int i = t + 256*l;
      float v = 0.f;
      if (i < NWT){
        int oc  = i % COUT;
        int k   = (i / COUT) % 9;
        int icl = i / (9*COUT);
        v = w[((size_t)oc*CIN + c0+icl)*9 + k];
      }
      wreg[l] = v;
    }
  };

  auto write_lds = [&](int bufi){
    #pragma unroll
    for (int l=0;l<NLD4;++l){
      int i = t + 256*l;
      if (i < NH4){
        int c = i/(HR*NB4), rm = i - c*(HR*NB4);
        int r = rm/NB4, m = rm - r*NB4;
        *(float4*)(&ildsb[bufi*(ICCH*ILDSC) + c*ILDSC + r*PADC + 4*((r>>2)&1) + 4*m]) = hreg[l];
      }
    }
    #pragma unroll
    for (int l=0;l<NLD1;++l){
      int i = t + 256*l;
      if (i < NH1){
        int c = i/HR, r = i - c*HR;
        ildsb[bufi*(ICCH*ILDSC) + c*ILDSC + r*PADC + 4*((r>>2)&1) + NB4*4] = treg[l];
      }
    }
    #pragma unroll
    for (int l=0;l<NLDW;++l){
      int i = t + 256*l;
      if (i < NWT) wldsb[bufi*NWT + i] = wreg[l];
    }
  };

  float acc[C][2][4];
  #pragma unroll
  for (int j=0;j<C;++j){
    float bv = bias[og*C+j];
    #pragma unroll
    for (int py=0;py<2;++py)
      #pragma unroll
      for (int px=0;px<4;++px) acc[j][py][px]=bv;
  }

  load_regs(0);
  write_lds(0);
  __syncthreads();

  #pragma unroll 1
  for (int ch=0; ch<NCH; ++ch){
    const int cur = ch & 1;
    if (ch+1 < NCH) load_regs((ch+1)*ICCH);

    #pragma unroll 1
    for (int icl=0; icl<ICCH; ++icl){
      const float* wpb = &wldsb[cur*NWT + icl*9*COUT] + og*C;
      float4 wk0[9];
      #pragma unroll
      for (int k=0;k<9;++k) wk0[k] = *(const float4*)(wpb + k*COUT);
      const float* ipb = &ildsb[cur*(ICCH*ILDSC) + icl*ILDSC] + 8*sx;
      float rw[5][12];
      #pragma unroll
      for (int r=0;r<5;++r){
        const int rr = 4*sy + r;
        const float* rp = ipb + rr*PADC + 4*((rr>>2)&1);
        #pragma unroll
        for (int m=0;m<3;++m){
          float4 v4 = *(const float4*)(rp + 4*m);
          rw[r][4*m+0]=v4.x; rw[r][4*m+1]=v4.y; rw[r][4*m+2]=v4.z; rw[r][4*m+3]=v4.w;
        }
      }
      #pragma unroll
      for (int py=0;py<2;++py)
        #pragma unroll
        for (int ky=0;ky<3;++ky)
          #pragma unroll
          for (int kx=0;kx<3;++kx){
            const float4 wa = wk0[ky*3+kx];
            #pragma unroll
            for (int px=0;px<4;++px){
              const float xv = rw[2*py+ky][2*px+kx];
              acc[0][py][px] += xv*wa.x; acc[1][py][px] += xv*wa.y;
              acc[2][py][px] += xv*wa.z; acc[3][py][px] += xv*wa.w;
            }
          }
    }

    if (ch+1 < NCH) write_lds((ch+1)&1);
    __syncthreads();
  }

  // ---- epilogue: SiLU -> LDS f3 tile (stride 68)
  #pragma unroll
  for (int j=0;j<C;++j){
    int oc = og*C+j;
    #pragma unroll
    for (int py=0;py<2;++py)
      #pragma unroll
      for (int px=0;px<4;++px){
        int pxidx = (sy*2+py)*16 + sx*4+px;
        float z = acc[j][py][px];
        f3l[pxidx*68 + oc] = z/(1.0f+expf(-z));
      }
  }
  __syncthreads();

  // ---- head (6 channels) + sigmoid + decode + write
  const float awv[3] = {4.0f, 8.0f, 13.0f};
  const float ahv[3] = {5.0f, 10.0f, 16.0f};
  for (int q=t; q<384; q+=256){
    int a = q >> 7, p = q & 127;
    float ac[6];
    #pragma unroll
    for (int j=0;j<6;++j) ac[j] = bhl[a*6+j];
    const float* fp = f3l + p*68;
    const float* wp = whl + a*6*64;
    #pragma unroll 4
    for (int ic=0; ic<64; ic+=4){
      float4 fv = *(const float4*)(fp + ic);
      #pragma unroll
      for (int j=0;j<6;++j){
        float4 wv = *(const float4*)(wp + j*64 + ic);
        ac[j] += fv.x*wv.x; ac[j] += fv.y*wv.y;
        ac[j] += fv.z*wv.z; ac[j] += fv.w*wv.w;
      }
    }
    float p0 = sigmoidf_(ac[0]);
    float p1 = sigmoidf_(ac[1]);
    float p2 = sigmoidf_(ac[2]);
    float p3 = sigmoidf_(ac[3]);
    float p4 = sigmoidf_(ac[4]);
    float p15= sigmoidf_(ac[5]);
    int gx = bx*16 + (p & 15), gy = by*8 + (p >> 4);
    float cx = (p0*2.0f - 0.5f + (float)gx)*8.0f;
    float cy = (p1*2.0f - 0.5f + (float)gy)*8.0f;
    float ww = p2*2.0f; ww = ww*ww*awv[a];
    float hh = p3*2.0f; hh = hh*hh*ahv[a];
    float sc = p4*p15;
    sc = (sc > 0.5f) ? sc : 0.0f;
    int bi = a*GRID*GRID + gy*GRID + gx;
    float* bo = boxes + ((size_t)b*NBOX + bi)*4;
    bo[0] = cx - ww*0.5f;
    bo[1] = cy - hh*0.5f;
    bo[2] = cx + ww*0.5f;
    bo[3] = cy + hh*0.5f;
    scores[(size_t)b*NBOX + bi] = sc;
  }
}

// ---------------- kernel A: compact + bitonic-sort top-K + gather ----------------
__global__ __launch_bounds__(1024) void topk_kernel(
    const float* __restrict__ boxes, const float* __restrict__ scores,
    float* __restrict__ nmsbuf, int* __restrict__ mcnt)
{
  __shared__ unsigned long long keys[SORT_CAP];  // 64 KB
  __shared__ int   cntM;
  __shared__ int   sel[KTOP];
  __shared__ float selsc[KTOP];
  __shared__ int   wsum[16];
  __shared__ float rs[16];
  __shared__ int   ri[16];
  __shared__ unsigned clm[(NBOX+31)/32];

  const int b = blockIdx.x;
  const int t = threadIdx.x;
  const int lane = t & 63, wv = t >> 6;
  const float* scp = scores + (size_t)b*NBOX;

  if (t == 0) cntM = 0;
  __syncthreads();

  for (int i=t; i<NBOX; i+=1024){
    float v = scp[i];
    if (v > 0.0f){
      int p = atomicAdd(&cntM, 1);
      if (p < SORT_CAP)
        keys[p] = ((unsigned long long)__float_as_uint(v) << 32)
                | (unsigned)(0xFFFFFFFFu - (unsigned)i);
    }
  }
  __syncthreads();
  const int M = cntM;
  if (t == 0) mcnt[b] = M;

  if (M <= SORT_CAP){
    int P = 64; while (P < M) P <<= 1;
    for (int i=t; i<P; i+=1024) if (i >= M) keys[i] = 0ULL;
    __syncthreads();
    for (int k=2; k<=P; k<<=1){
      for (int j=k>>1; j>0; j>>=1){
        for (int i=t; i<P; i+=1024){
          int ixj = i ^ j;
          if (ixj > i){
            unsigned long long a = keys[i], c = keys[ixj];
            bool up = ((i & k) == 0);
            if (up ? (a < c) : (a > c)){ keys[i] = c; keys[ixj] = a; }
          }
        }
        __syncthreads();
      }
    }
    const int top = (M < KTOP) ? M : KTOP;
    if (t < top){
      unsigned long long kk = keys[t];
      selsc[t] = __uint_as_float((unsigned)(kk >> 32));
      sel[t]   = (int)(0xFFFFFFFFu - (unsigned)(kk & 0xFFFFFFFFu));
    }
    if (M < KTOP){
      const int need = KTOP - M;
      const int Cc = (NBOX + 1023)/1024;
      int lo = t*Cc, hi = lo+Cc; if (hi > NBOX) hi = NBOX; if (lo > NBOX) lo = NBOX;
      int zc = 0;
      for (int i=lo;i<hi;i++) if (scp[i] <= 0.0f) zc++;
      int v = zc;
      #pragma unroll
      for (int off=1; off<64; off<<=1){
        int n = __shfl_up(v, off);
        if (lane >= off) v += n;
      }
      if (lane == 63) wsum[wv] = v;
      __syncthreads();
      if (t == 0){
        int a = 0;
        for (int w=0; w<16; w++){ int tmp = wsum[w]; wsum[w] = a; a += tmp; }
      }
      __syncthreads();
      int r = wsum[wv] + v - zc;
      for (int i=lo;i<hi;i++){
        if (scp[i] <= 0.0f){
          if (r < need){ sel[M+r] = i; selsc[M+r] = 0.0f; }
          r++;
        }
      }
    }
    __syncthreads();
  } else {
    for (int i=t; i<(NBOX+31)/32; i+=1024) clm[i] = 0u;
    __syncthreads();
    for (int k=0;k<KTOP;k++){
      float best = -2.0f; int bi = NBOX;
      for (int i=t;i<NBOX;i+=1024){
        if (!((clm[i>>5] >> (i&31)) & 1u)){
          float v = scp[i];
          if (v > best){ best=v; bi=i; }
        }
      }
      #pragma unroll
      for (int off=32; off>0; off>>=1){
        float ov = __shfl_down(best, off);
        int   oi = __shfl_down(bi,   off);
        if (ov > best || (ov == best && oi < bi)){ best=ov; bi=oi; }
      }
      if (lane == 0){ rs[wv]=best; ri[wv]=bi; }
      __syncthreads();
      if (t == 0){
        for (int w=1; w<16; w++)
          if (rs[w] > best || (rs[w] == best && ri[w] < bi)){ best=rs[w]; bi=ri[w]; }
        sel[k]=bi; selsc[k]=best; clm[bi>>5] |= (1u << (bi&31));
      }
      __syncthreads();
    }
  }

  if (t < KTOP){
    const float* bp = boxes + ((size_t)b*NBOX + sel[t])*4;
    float x1=bp[0], y1=bp[1], x2=bp[2], y2=bp[3];
    float* o = nmsbuf + ((size_t)b*KTOP + t)*6;
    o[0]=x1; o[1]=y1; o[2]=x2; o[3]=y2;
    o[4]=selsc[t];
    o[5]=fmaxf(x2-x1,0.0f)*fmaxf(y2-y1,0.0f);
  }
}

// ---------------- kernel B: single-wave register NMS + final write ----------------
__global__ __launch_bounds__(64, 1) void nms_kernel(
    const float* __restrict__ nmsbuf, const int* __restrict__ mcnt,
    float* __restrict__ out)
{
  const int b = blockIdx.x;
  const int lane = threadIdx.x;
  int Mtop = mcnt[b]; if (Mtop > KTOP) Mtop = KTOP;
  float X1[5],Y1[5],X2[5],Y2[5],AR[5],SC[5];
  unsigned keepm = 0;
  #pragma unroll
  for (int s5=0; s5<5; ++s5){
    int j = lane + 64*s5;
    if (j < KTOP){
      const float* p = nmsbuf + ((size_t)b*KTOP + j)*6;
      X1[s5]=p[0]; Y1[s5]=p[1]; X2[s5]=p[2]; Y2[s5]=p[3];
      SC[s5]=p[4]; AR[s5]=p[5];
      keepm |= (1u << s5);
    } else { X1[s5]=0;Y1[s5]=0;X2[s5]=0;Y2[s5]=0;AR[s5]=0;SC[s5]=0; }
  }
  for (int i=0;i<Mtop;i++){
    const int iw = i & 63, is = i >> 6;
    unsigned km = __shfl(keepm, iw);
    if ((km >> is) & 1u){
      float sx1 = (is==0)?X1[0]:(is==1)?X1[1]:(is==2)?X1[2]:(is==3)?X1[3]:X1[4];
      float sy1 = (is==0)?Y1[0]:(is==1)?Y1[1]:(is==2)?Y1[2]:(is==3)?Y1[3]:Y1[4];
      float sx2 = (is==0)?X2[0]:(is==1)?X2[1]:(is==2)?X2[2]:(is==3)?X2[3]:X2[4];
      float sy2 = (is==0)?Y2[0]:(is==1)?Y2[1]:(is==2)?Y2[2]:(is==3)?Y2[3]:Y2[4];
      float sa  = (is==0)?AR[0]:(is==1)?AR[1]:(is==2)?AR[2]:(is==3)?AR[3]:AR[4];
      float bx1=__shfl(sx1,iw), by1=__shfl(sy1,iw);
      float bx2=__shfl(sx2,iw), by2=__shfl(sy2,iw);
      float ba =__shfl(sa ,iw);
      #pragma unroll
      for (int s5=0; s5<5; ++s5){
        int j = lane + 64*s5;
        if (((keepm >> s5) & 1u) && j > i){
          float ix1=fmaxf(bx1,X1[s5]);
          float iy1=fmaxf(by1,Y1[s5]);
          float ix2=fminf(bx2,X2[s5]);
          float iy2=fminf(by2,Y2[s5]);
          float inter=fmaxf(ix2-ix1,0.0f)*fmaxf(iy2-iy1,0.0f);
          float iou = inter/(ba+AR[s5]-inter+1e-7f);
          if (iou > 0.5f) keepm &= ~(1u << s5);
        }
      }
    }
  }
  #pragma unroll
  for (int s5=0; s5<5; ++s5){
    int j = lane + 64*s5;
    if (j < KTOP){
      float scv = SC[s5];
      float kf  = (((keepm >> s5) & 1u) && scv > 0.0f) ? 1.0f : 0.0f;
      float* o = out + ((size_t)b*KTOP + j)*6;
      o[0]=X1[s5]; o[1]=Y1[s5]; o[2]=X2[s5]; o[3]=Y2[s5];
      o[4]=scv; o[5]=kf;
    }
  }
}

extern "C" void kernel_launch(void* const* d_in, const int* in_sizes, int n_in,
                              void* d_out, int out_size, void* d_ws, size_t ws_size,
                              hipStream_t stream) {
  const float* x  = (const float*)d_in[0];
  const float* W1 = (const float*)d_in[1];
  const float* b1 = (const float*)d_in[2];
  const float* W2 = (const float*)d_in[3];
  const float* b2 = (const float*)d_in[4];
  const float* W3 = (const float*)d_in[5];
  const float* b3 = (const float*)d_in[6];
  const float* Wh = (const float*)d_in[7];
  const float* bh = (const float*)d_in[8];
  float* out = (float*)d_out;
  float* ws  = (float*)d_ws;

  float* f1     = ws;               // 16x16x320x320 = 26,214,400
  float* f2     = ws + 26214400;    // 16x32x160x160 = 13,107,200
  float* boxes  = ws;               // reuse f1 region: 16x19200x4 (f1 dead after conv2)
  float* scores = boxes + 1228800;  // 16x19200
  float* nmsbuf = scores + 307200;  // 16x300x6
  int*   mcnt   = (int*)(nmsbuf + 28800);

  // conv1: 3->16, tile 64x16, C=8, ICCH=1, MINW=1 -> 1600 blocks
  conv3x3s2_v7<3,16,8,1,640,320,64,16,1><<<5*20*BATCH, 256, 0, stream>>>(x,  W1, b1, f1);
  // conv2: 16->32, tile 32x16, C=8, ICCH=2, MINW=4 (VGPR<=128 experiment) -> 800 blocks
  conv3x3s2_v7<16,32,8,2,320,160,32,16,4><<<5*10*BATCH, 256, 0, stream>>>(f1, W2, b2, f2);
  // conv3 + head + decode fused -> 800 blocks (f3 never hits HBM)
  conv3_decode_fused<<<5*10*BATCH, 256, 0, stream>>>(f2, W3, b3, Wh, bh, boxes, scores);

  topk_kernel<<<BATCH, 1024, 0, stream>>>(boxes, scores, nmsbuf, mcnt);
  nms_kernel<<<BATCH, 64, 0, stream>>>(nmsbuf, mcnt, out);
}